// Round 8
// baseline (423.835 us; speedup 1.0000x reference)
//
#include <hip/hip_runtime.h>
#include <stdint.h>

#define NN 10000
#define NE 160000
#define MPAD 10112   // 79 * 128 = 158 * 64
#define MTILES 79

typedef unsigned short u16;
typedef float f32x4 __attribute__((ext_vector_type(4)));
typedef short short8 __attribute__((ext_vector_type(8)));
typedef __bf16 bf16x8 __attribute__((ext_vector_type(8)));
typedef unsigned short u16x4 __attribute__((ext_vector_type(4)));
typedef unsigned short u16x8 __attribute__((ext_vector_type(8)));

__device__ __forceinline__ float bf2f(u16 u) {
  union { unsigned u; float f; } c; c.u = ((unsigned)u) << 16; return c.f;
}
__device__ __forceinline__ u16 f2bf(float f) {
  union { float f; unsigned u; } c; c.f = f;
  return (u16)((c.u + 0x7FFFu + ((c.u >> 16) & 1u)) >> 16);
}

// ---------------- CSR build ----------------
__global__ __launch_bounds__(256) void deg_count(const int* __restrict__ dst, int* __restrict__ deg) {
  int e = blockIdx.x * 256 + threadIdx.x;
  if (e < NE) atomicAdd(&deg[dst[e]], 1);
}

__global__ __launch_bounds__(256) void scan_off(const int* __restrict__ deg,
                                                int* __restrict__ roff, int* __restrict__ cur) {
  __shared__ int part[256];
  const int t = threadIdx.x;
  const int CH = 40;
  int s = 0;
  for (int i = 0; i < CH; ++i) { int idx = t * CH + i; if (idx < NN) s += deg[idx]; }
  part[t] = s; __syncthreads();
  for (int off = 1; off < 256; off <<= 1) {
    int v = (t >= off) ? part[t - off] : 0;
    __syncthreads(); part[t] += v; __syncthreads();
  }
  int run = (t == 0) ? 0 : part[t - 1];
  for (int i = 0; i < CH; ++i) {
    int idx = t * CH + i;
    if (idx < NN) { roff[idx] = run; cur[idx] = run; run += deg[idx]; }
  }
  if (t == 255) roff[NN] = NE;
}

__global__ __launch_bounds__(256) void fill_csr(const int* __restrict__ src, const int* __restrict__ dst,
                                                int* __restrict__ cur, int* __restrict__ esrc) {
  int e = blockIdx.x * 256 + threadIdx.x;
  if (e < NE) {
    int p = atomicAdd(&cur[dst[e]], 1);
    esrc[p] = src[e];
  }
}

// ---------------- conversions ----------------
__global__ __launch_bounds__(256) void convert_h(const float* __restrict__ h, u16* __restrict__ hbf) {
  const size_t i = (size_t)(blockIdx.x * 256 + threadIdx.x) * 4;
  if (i >= (size_t)MPAD * 960) return;
  u16x4 o;
  if (i < (size_t)NN * 960) {
    float4 v = *(const float4*)(h + i);
    o[0] = f2bf(v.x); o[1] = f2bf(v.y); o[2] = f2bf(v.z); o[3] = f2bf(v.w);
  } else {
    o[0] = 0; o[1] = 0; o[2] = 0; o[3] = 0;
  }
  *(u16x4*)(hbf + i) = o;
}

// weight transposes, K-concat capable: out[c*ldo + koff + r] = bf16(in[r][c])
struct WDesc { const float* in; u16* out; int R, C, Cpad, ldo, koff; };
struct WPack { WDesc d[7]; };

__global__ __launch_bounds__(256) void transpose_all(WPack p) {
  const WDesc w = p.d[blockIdx.z];
  const int cb = blockIdx.x * 32, rb = blockIdx.y * 32;
  if (cb >= w.Cpad || rb >= w.R) return;
  __shared__ float tile[32][33];
  const int tx = threadIdx.x & 31, ty = threadIdx.x >> 5;
  for (int i = ty; i < 32; i += 8) {
    int r = rb + i, c = cb + tx;
    tile[i][tx] = (r < w.R && c < w.C) ? w.in[(size_t)r * w.C + c] : 0.f;
  }
  __syncthreads();
  for (int i = ty; i < 32; i += 8) {
    int c = cb + i, r = rb + tx;
    if (c < w.Cpad && r < w.R) w.out[(size_t)c * w.ldo + w.koff + r] = f2bf(tile[tx][i]);
  }
}

// ---------------- GEMM: Cb = act(([A0|A1]) @ B^T + bias) ----------------
// Reg-staging (T14): global_load_dwordx4 -> VGPR -> ds_write_b128, bypassing
// the serialized per-block global_load_lds DMA queue (rounds 0-5 model).
// ROUND-7 FAILURE MODE (fixed here): compiler allocated 64 VGPR (8 waves/EU
// on its own) and spilled the staging reg sets to scratch inside the K-loop
// (WRITE_SIZE 10->47MB, FETCH +8MB). Fixes: (a) phase/gload/dswrite are now
// MACROS - rA/rB identity is lexical, all indices compile-time (rule #20);
// (b) amdgpu_waves_per_eu(4,4) pins 4 waves/EU -> full 128-VGPR budget,
// no occupancy-seeking squeeze. Demand ~124 <= 128.
// Pipeline: 8 waves, BK=64, two 32KB buffers, ONE barrier per phase:
//   barrier          // S[t&1]=tile t visible; prev readers of S[(t+1)&1] done
//   ds_read tile t   // 12 x b128
//   gload t+2 -> set[t&1]          (4 x dwordx4, linear, coalesced)
//   vmcnt(4)         // set[(t+1)&1] (tile t+1, issued last phase) landed
//   ds_write set[(t+1)&1] -> S[(t+1)&1]
//   lgkmcnt(0)       // frags in regs + writes retired
//   MFMA x16
// Buffer safety: S[(t+1)&1]'s readers (phase t-1) drained lgkm before this
// phase's barrier. Odd-nsteps tail guard kept (round-6 bug: G1 K=960 ->
// nsteps=15). Swizzle on ds_write address (phys slot = sslot ^ (row&7));
// global source LINEAR; ds_read side same XOR involution.
template<int TM, int TN>
__global__ __launch_bounds__(512) __attribute__((amdgpu_waves_per_eu(4, 4)))
void gemm3(
    const u16* __restrict__ A0, int lda0,
    const u16* __restrict__ A1, int lda1, int ksplit,
    const u16* __restrict__ B,
    const float* __restrict__ bias, int nbias,
    u16* __restrict__ Cb, int ldcb,
    int K, int act, int tiles_n) {
  constexpr int TR = TM + TN;        // staged rows per K-tile (256)
  constexpr int WCOLS = 4;           // 8 waves: 2 rows x 4 cols
  constexpr int WN = TN / WCOLS;     // 32
  constexpr int NJ = WN / 16;        // 2
  constexpr int MT = MPAD / TM;      // M tiles
  __shared__ __align__(16) u16 S0[TR * 64];
  __shared__ __align__(16) u16 S1[TR * 64];
  const int tid = threadIdx.x;
  const int wave = tid >> 6, lane = tid & 63;

  // bijective XCD-chunked swizzle over col-fastest linear id (m204)
  const int nwg = tiles_n * MT;
  const int orig = blockIdx.x + blockIdx.y * tiles_n;
  const int q = nwg >> 3, r8 = nwg & 7;
  const int xcd = orig & 7, idx = orig >> 3;
  const int wg = (xcd < r8 ? xcd * (q + 1) : r8 * (q + 1) + (xcd - r8) * q) + idx;
  const int tm = (wg / tiles_n) * TM;
  const int tn = (wg % tiles_n) * TN;

  const int wr = (wave / WCOLS) * 64;
  const int wc = (wave % WCOLS) * WN;
  const int fr = lane & 15, fq = lane >> 4;
  const int sr8 = lane >> 3;         // row within 8-row wave chunk
  const int sslot = lane & 7;        // 16B slot within 128B row
  f32x4 acc[4][NJ] = {};

  const int nsteps = K >> 6;          // BK=64; K % 64 == 0 in all uses

// linear coalesced global loads: lanes 0..7 sweep one 128B row
#define GLOADV(r, kkx)                                                        \
  {                                                                           \
    const int kk_ = (kkx);                                                    \
    _Pragma("unroll")                                                         \
    for (int c = 0; c < 4; ++c) {                                             \
      const int row_ = c * 64 + wave * 8 + sr8;                               \
      if (c < TM / 64) {                                                      \
        r[c] = (kk_ < ksplit)                                                 \
            ? *(const u16x8*)&A0[(size_t)(tm + row_) * lda0 + kk_ + sslot * 8]\
            : *(const u16x8*)&A1[(size_t)(tm + row_) * lda1 + (kk_ - ksplit) + sslot * 8]; \
      } else {                                                                \
        r[c] = *(const u16x8*)&B[(size_t)(tn + row_ - TM) * (size_t)K + kk_ + sslot * 8];  \
      }                                                                       \
    }                                                                         \
  }

// swizzled LDS write: phys slot = sslot ^ (row&7); row&7 == sr8
#define DSWRITE(Sw, r)                                                        \
  {                                                                           \
    _Pragma("unroll")                                                         \
    for (int c = 0; c < 4; ++c) {                                             \
      const int row_ = c * 64 + wave * 8 + sr8;                               \
      *(u16x8*)&Sw[row_ * 64 + ((sslot ^ sr8) << 3)] = r[c];                  \
    }                                                                         \
  }

// one phase; wset holds raw tile t+1 (to write), lset receives tile t+2
#define PHASE(tx, Sr, Sw, wset, lset)                                         \
  {                                                                           \
    const int t_ = (tx);                                                      \
    __builtin_amdgcn_s_barrier();                                             \
    __builtin_amdgcn_sched_barrier(0);                                        \
    short8 af[4][2], bfr[2][NJ];                                              \
    _Pragma("unroll")                                                         \
    for (int i = 0; i < 4; ++i) {                                             \
      const int r_ = wr + i * 16 + fr;                                        \
      _Pragma("unroll")                                                       \
      for (int kc = 0; kc < 2; ++kc)                                          \
        af[i][kc] = *(const short8*)&Sr[r_ * 64 + ((((kc << 2) | fq) ^ (r_ & 7)) << 3)]; \
    }                                                                         \
    _Pragma("unroll")                                                         \
    for (int j = 0; j < NJ; ++j) {                                            \
      const int r_ = TM + wc + j * 16 + fr;                                   \
      _Pragma("unroll")                                                       \
      for (int kc = 0; kc < 2; ++kc)                                          \
        bfr[kc][j] = *(const short8*)&Sr[r_ * 64 + ((((kc << 2) | fq) ^ (r_ & 7)) << 3)]; \
    }                                                                         \
    __builtin_amdgcn_sched_barrier(0);                                        \
    if (t_ + 2 < nsteps) GLOADV(lset, (t_ + 2) << 6);                         \
    __builtin_amdgcn_sched_barrier(0);                                        \
    if (t_ + 1 < nsteps) {                                                    \
      if (t_ + 2 < nsteps) {                                                  \
        asm volatile("s_waitcnt vmcnt(4)" ::: "memory");                      \
      } else {                                                                \
        asm volatile("s_waitcnt vmcnt(0)" ::: "memory");                      \
      }                                                                       \
      DSWRITE(Sw, wset);                                                      \
    }                                                                         \
    asm volatile("s_waitcnt lgkmcnt(0)" ::: "memory");                        \
    __builtin_amdgcn_sched_barrier(0);                                        \
    __builtin_amdgcn_s_setprio(1);                                            \
    _Pragma("unroll")                                                         \
    for (int kc = 0; kc < 2; ++kc)                                            \
      _Pragma("unroll")                                                       \
      for (int i = 0; i < 4; ++i)                                             \
        _Pragma("unroll")                                                     \
        for (int j = 0; j < NJ; ++j)                                          \
          acc[i][j] = __builtin_amdgcn_mfma_f32_16x16x32_bf16(                \
              __builtin_bit_cast(bf16x8, af[i][kc]),                          \
              __builtin_bit_cast(bf16x8, bfr[kc][j]),                         \
              acc[i][j], 0, 0, 0);                                            \
    __builtin_amdgcn_s_setprio(0);                                            \
    __builtin_amdgcn_sched_barrier(0);                                        \
  }

  u16x8 rA[4], rB[4];
  GLOADV(rA, 0);                      // tile 0
  asm volatile("s_waitcnt vmcnt(0)" ::: "memory");
  DSWRITE(S0, rA);
  GLOADV(rB, 64);                     // tile 1 (nsteps >= 8 always)
  asm volatile("s_waitcnt lgkmcnt(0)" ::: "memory");  // S0 writes retired

  for (int base = 0; base < nsteps; base += 2) {
    PHASE(base, S0, S1, rB, rA);                       // write t+1 (rB), load t+2 -> rA
    if (base + 1 < nsteps)                             // K=960 -> nsteps=15 is ODD
      PHASE(base + 1, S1, S0, rA, rB);                 // write t+2 (rA), load t+3 -> rB
  }
#undef PHASE
#undef DSWRITE
#undef GLOADV

  // C/D layout: col=lane&15, row=(lane>>4)*4+reg (m89/m91 verified)
  const int cr = fq * 4, cc = fr;
#pragma unroll
  for (int i = 0; i < 4; ++i)
#pragma unroll
    for (int j = 0; j < NJ; ++j) {
      const int col = tn + wc + j * 16 + cc;
      const float bv = (col < nbias) ? bias[col] : 0.f;
#pragma unroll
      for (int r = 0; r < 4; ++r) {
        const int row = tm + wr + i * 16 + cr + r;
        float v = acc[i][j][r] + bv;
        if (act) v = fmaxf(v, 0.f);
        Cb[(size_t)row * ldcb + col] = f2bf(v);
      }
    }
}

// ---------------- segment max, XCD feature-sliced ----------------
// Feature dim split into 8 slices of CW; slice c pinned to XCD c via
// blockIdx.x & 7. Per-XCD working set MPAD*CW*2B = 2.6MB/1.3MB < 4MB L2.
// relu'd bf16 >= 0: u16 compare == float compare; 0 == empty-segment fill.
template<int CW>
__global__ __launch_bounds__(256) void aggregate_xcd(
    const u16* __restrict__ m, int ldm, const int* __restrict__ roff,
    const int* __restrict__ esrc, u16* __restrict__ neigh, int ldn) {
  constexpr int TPN = CW / 8;          // threads per node
  constexpr int NPB = 256 / TPN;       // nodes per block
  const int chunk = blockIdx.x & 7;
  const int node = (blockIdx.x >> 3) * NPB + threadIdx.x / TPN;
  if (node >= NN) return;
  const int fi = chunk * CW + (threadIdx.x % TPN) * 8;
  const int beg = roff[node], end = roff[node + 1];
  u16x8 a;
#pragma unroll
  for (int i = 0; i < 8; ++i) a[i] = 0;
  for (int e = beg; e < end; ++e) {
    const u16* row = m + (size_t)esrc[e] * ldm;
    u16x8 v = *(const u16x8*)(row + fi);
#pragma unroll
    for (int i = 0; i < 8; ++i) a[i] = (v[i] > a[i]) ? v[i] : a[i];
  }
  *(u16x8*)(neigh + (size_t)node * ldn + fi) = a;
}

// ---------------- layer 2 output: sigmoid(x2 . Ws2 + neigh2 . Wn2 + b2) ----------------
__global__ __launch_bounds__(256) void final_out(
    const u16* __restrict__ x, const u16* __restrict__ neigh,
    const float* __restrict__ ws, const float* __restrict__ wn,
    const float* __restrict__ b, float* __restrict__ out) {
  const int wave = threadIdx.x >> 6, lane = threadIdx.x & 63;
  const int n = blockIdx.x * 4 + wave;
  if (n >= NN) return;
  const int f = lane * 8;
  const u16* xr = x + (size_t)n * 512 + f;
  const u16* nr = neigh + (size_t)n * 512 + f;
  float s = 0.f;
#pragma unroll
  for (int i = 0; i < 8; ++i)
    s += bf2f(xr[i]) * ws[f + i] + bf2f(nr[i]) * wn[f + i];
#pragma unroll
  for (int o = 32; o > 0; o >>= 1) s += __shfl_xor(s, o);
  if (lane == 0) out[n] = 1.f / (1.f + expf(-(s + b[0])));
}

extern "C" void kernel_launch(void* const* d_in, const int* in_sizes, int n_in,
                              void* d_out, int out_size, void* d_ws, size_t ws_size,
                              hipStream_t stream) {
  const float* h   = (const float*)d_in[0];
  const int*   src = (const int*)d_in[1];
  const int*   dst = (const int*)d_in[2];
  const float* Wp0 = (const float*)d_in[3];
  const float* bp0 = (const float*)d_in[4];
  const float* Ws0 = (const float*)d_in[5];
  const float* Wn0 = (const float*)d_in[6];
  const float* b0  = (const float*)d_in[7];
  const float* Wp1 = (const float*)d_in[8];
  const float* bp1 = (const float*)d_in[9];
  const float* Ws1 = (const float*)d_in[10];
  const float* Wn1 = (const float*)d_in[11];
  const float* b1  = (const float*)d_in[12];
  const float* Wp2 = (const float*)d_in[13];
  const float* bp2 = (const float*)d_in[14];
  const float* Ws2 = (const float*)d_in[15];
  const float* Wn2 = (const float*)d_in[16];
  const float* b2  = (const float*)d_in[17];
  float* out = (float*)d_out;

  char* ws = (char*)d_ws;
  size_t off = 0;
  auto alloc = [&](size_t n) { char* p = ws + off; off = (off + n + 255) & ~(size_t)255; return p; };
  u16* hbf   = (u16*)alloc((size_t)MPAD * 960 * 2);
  u16* x1    = (u16*)alloc((size_t)MPAD * 512 * 2);
  u16* x2    = (u16*)alloc((size_t)MPAD * 512 * 2);
  u16* mbuf  = (u16*)alloc((size_t)MPAD * 1024 * 2);
  u16* nbuf  = (u16*)alloc((size_t)MPAD * 1024 * 2);
  u16* WpT0  = (u16*)alloc((size_t)1024 * 960 * 2);   // [1024 cols][K=960]
  u16* Bcat0 = (u16*)alloc((size_t)512 * 1920 * 2);   // [512][Ws0(960) ; Wn0(960)]
  u16* WpT1  = (u16*)alloc((size_t)512 * 512 * 2);
  u16* Bcat1 = (u16*)alloc((size_t)512 * 1024 * 2);   // [512][Ws1(512) ; Wn1(512)]
  u16* WpT2  = (u16*)alloc((size_t)512 * 512 * 2);
  int* deg   = (int*)alloc(NN * 4);
  int* roff  = (int*)alloc((NN + 1) * 4);
  int* curp  = (int*)alloc(NN * 4);
  int* esrc  = (int*)alloc(NE * 4);

  hipMemsetAsync(deg, 0, NN * 4, stream);
  deg_count<<<NE / 256, 256, 0, stream>>>(dst, deg);
  scan_off<<<1, 256, 0, stream>>>(deg, roff, curp);
  fill_csr<<<NE / 256, 256, 0, stream>>>(src, dst, curp, esrc);
  convert_h<<<(MPAD * 960 / 4) / 256, 256, 0, stream>>>(h, hbf);

  WPack wp;
  wp.d[0] = {Wp0, WpT0,  960, 960, 1024,  960,   0};
  wp.d[1] = {Ws0, Bcat0, 960, 512,  512, 1920,   0};
  wp.d[2] = {Wn0, Bcat0, 960, 512,  512, 1920, 960};
  wp.d[3] = {Wp1, WpT1,  512, 512,  512,  512,   0};
  wp.d[4] = {Ws1, Bcat1, 512, 512,  512, 1024,   0};
  wp.d[5] = {Wn1, Bcat1, 512, 512,  512, 1024, 512};
  wp.d[6] = {Wp2, WpT2,  512, 512,  512,  512,   0};
  transpose_all<<<dim3(32, 30, 7), 256, 0, stream>>>(wp);

  // ---- layer 0 (960 -> 512) ----
  // G1: m0 = relu(hbf @ Wp0 + bp0)  [N=1024 padded, 960 real]
  gemm3<128, 128><<<dim3(8, 79), 512, 0, stream>>>(
      hbf, 960, hbf, 960, 960, WpT0, bp0, 960, mbuf, 1024, 960, 1, 8);
  aggregate_xcd<128><<<5000, 256, 0, stream>>>(mbuf, 1024, roff, esrc, nbuf, 1024);
  // G2: x1 = relu([hbf | nbuf] @ [Ws0;Wn0] + b0)  K = 1920
  gemm3<128, 128><<<dim3(4, 79), 512, 0, stream>>>(
      hbf, 960, nbuf, 1024, 960, Bcat0, b0, 512, x1, 512, 1920, 1, 4);

  // ---- layer 1 (512 -> 512) ----
  gemm3<128, 128><<<dim3(4, 79), 512, 0, stream>>>(
      x1, 512, x1, 512, 512, WpT1, bp1, 512, mbuf, 512, 512, 1, 4);
  aggregate_xcd<64><<<2504, 256, 0, stream>>>(mbuf, 512, roff, esrc, nbuf, 512);
  gemm3<128, 128><<<dim3(4, 79), 512, 0, stream>>>(
      x1, 512, nbuf, 512, 512, Bcat1, b1, 512, x2, 512, 1024, 1, 4);

  // ---- layer 2 (512 -> 1) ----
  gemm3<128, 128><<<dim3(4, 79), 512, 0, stream>>>(
      x2, 512, x2, 512, 512, WpT2, bp2, 512, mbuf, 512, 512, 1, 4);
  aggregate_xcd<64><<<2504, 256, 0, stream>>>(mbuf, 512, roff, esrc, nbuf, 512);
  final_out<<<2500, 256, 0, stream>>>(x2, nbuf, Ws2, Wn2, b2, out);
}

// Round 9
// 336.298 us; speedup vs baseline: 1.2603x; 1.2603x over previous
//
#include <hip/hip_runtime.h>
#include <stdint.h>

#define NN 10000
#define NE 160000
#define MPAD 10112   // 79 * 128 = 158 * 64
#define MTILES 79

typedef unsigned short u16;
typedef float f32x4 __attribute__((ext_vector_type(4)));
typedef short short8 __attribute__((ext_vector_type(8)));
typedef __bf16 bf16x8 __attribute__((ext_vector_type(8)));
typedef unsigned short u16x4 __attribute__((ext_vector_type(4)));
typedef unsigned short u16x8 __attribute__((ext_vector_type(8)));

__device__ __forceinline__ float bf2f(u16 u) {
  union { unsigned u; float f; } c; c.u = ((unsigned)u) << 16; return c.f;
}
__device__ __forceinline__ u16 f2bf(float f) {
  union { float f; unsigned u; } c; c.f = f;
  return (u16)((c.u + 0x7FFFu + ((c.u >> 16) & 1u)) >> 16);
}

// ---------------- CSR build ----------------
__global__ __launch_bounds__(256) void deg_count(const int* __restrict__ dst, int* __restrict__ deg) {
  int e = blockIdx.x * 256 + threadIdx.x;
  if (e < NE) atomicAdd(&deg[dst[e]], 1);
}

__global__ __launch_bounds__(256) void scan_off(const int* __restrict__ deg,
                                                int* __restrict__ roff, int* __restrict__ cur) {
  __shared__ int part[256];
  const int t = threadIdx.x;
  const int CH = 40;
  int s = 0;
  for (int i = 0; i < CH; ++i) { int idx = t * CH + i; if (idx < NN) s += deg[idx]; }
  part[t] = s; __syncthreads();
  for (int off = 1; off < 256; off <<= 1) {
    int v = (t >= off) ? part[t - off] : 0;
    __syncthreads(); part[t] += v; __syncthreads();
  }
  int run = (t == 0) ? 0 : part[t - 1];
  for (int i = 0; i < CH; ++i) {
    int idx = t * CH + i;
    if (idx < NN) { roff[idx] = run; cur[idx] = run; run += deg[idx]; }
  }
  if (t == 255) roff[NN] = NE;
}

__global__ __launch_bounds__(256) void fill_csr(const int* __restrict__ src, const int* __restrict__ dst,
                                                int* __restrict__ cur, int* __restrict__ esrc) {
  int e = blockIdx.x * 256 + threadIdx.x;
  if (e < NE) {
    int p = atomicAdd(&cur[dst[e]], 1);
    esrc[p] = src[e];
  }
}

// ---------------- conversions ----------------
__global__ __launch_bounds__(256) void convert_h(const float* __restrict__ h, u16* __restrict__ hbf) {
  const size_t i = (size_t)(blockIdx.x * 256 + threadIdx.x) * 4;
  if (i >= (size_t)MPAD * 960) return;
  u16x4 o;
  if (i < (size_t)NN * 960) {
    float4 v = *(const float4*)(h + i);
    o[0] = f2bf(v.x); o[1] = f2bf(v.y); o[2] = f2bf(v.z); o[3] = f2bf(v.w);
  } else {
    o[0] = 0; o[1] = 0; o[2] = 0; o[3] = 0;
  }
  *(u16x4*)(hbf + i) = o;
}

// weight transposes, K-concat capable: out[c*ldo + koff + r] = bf16(in[r][c])
struct WDesc { const float* in; u16* out; int R, C, Cpad, ldo, koff; };
struct WPack { WDesc d[7]; };

__global__ __launch_bounds__(256) void transpose_all(WPack p) {
  const WDesc w = p.d[blockIdx.z];
  const int cb = blockIdx.x * 32, rb = blockIdx.y * 32;
  if (cb >= w.Cpad || rb >= w.R) return;
  __shared__ float tile[32][33];
  const int tx = threadIdx.x & 31, ty = threadIdx.x >> 5;
  for (int i = ty; i < 32; i += 8) {
    int r = rb + i, c = cb + tx;
    tile[i][tx] = (r < w.R && c < w.C) ? w.in[(size_t)r * w.C + c] : 0.f;
  }
  __syncthreads();
  for (int i = ty; i < 32; i += 8) {
    int c = cb + i, r = rb + tx;
    if (c < w.Cpad && r < w.R) w.out[(size_t)c * w.ldo + w.koff + r] = f2bf(tile[tx][i]);
  }
}

// ---------------- GEMM: Cb = act(([A0|A1]) @ B^T + bias) ----------------
// Reg-staging (T14): global_load_dwordx4 -> VGPR -> ds_write_b128, bypassing
// the per-CU global_load_lds DMA ceiling (~14 B/cy/CU, rounds 0-5 model:
// r2's G1-vs-G2 within-run comparison showed per-block rate HALVES when
// blocks/CU doubles -> per-CU cap; total gemm time == staged bytes / 7.5TB/s).
// ROUNDS 7-8 FAILURE MODE (understood): gfx950 unified VGPR+AGPR file.
// Reported "64 VGPR" = 64 arch + 64 acc-AGPR = 128 total = EXACTLY the
// 4-waves/EU budget both launch_bounds(512,4) and waves_per_eu(4,4) pinned.
// Demand ~150 (acc 32 + af 32 + bfr 16 + rA/rB 32 + addressing) > 128 ->
// forced spill (WRITE_SIZE 47-54MB scratch). FIX: amdgpu_waves_per_eu(2,2)
// -> 1 block/CU, 256-reg unified budget, demand fits with headroom.
// 8 waves/block suffice for latency hiding: 32KB plain VMEM loads in
// flight/block ~100 B/cy potential >> 14 B/cy DMA ceiling.
// Pipeline: 8 waves, BK=64, two 32KB buffers, ONE barrier per phase:
//   barrier          // S[t&1]=tile t visible; prev readers of S[(t+1)&1] done
//   ds_read tile t   // 12 x b128
//   gload t+2 -> set[t&1]          (4 x dwordx4, linear, coalesced)
//   vmcnt(4)         // set[(t+1)&1] (tile t+1, issued last phase) landed
//   ds_write set[(t+1)&1] -> S[(t+1)&1]
//   lgkmcnt(0)       // frags in regs + writes retired
//   MFMA x16
// Buffer safety: S[(t+1)&1]'s readers (phase t-1) drained lgkm before this
// phase's barrier. Odd-nsteps tail guard kept (round-6 bug: G1 K=960 ->
// nsteps=15). Swizzle on ds_write address (phys slot = sslot ^ (row&7));
// global source LINEAR; ds_read side same XOR involution.
// PRE-COMMIT: if VGPR still 64 / scratch persists -> revert to round-5
// (251.2us) permanently; this thread closes.
template<int TM, int TN>
__global__ __launch_bounds__(512) __attribute__((amdgpu_waves_per_eu(2, 2)))
void gemm3(
    const u16* __restrict__ A0, int lda0,
    const u16* __restrict__ A1, int lda1, int ksplit,
    const u16* __restrict__ B,
    const float* __restrict__ bias, int nbias,
    u16* __restrict__ Cb, int ldcb,
    int K, int act, int tiles_n) {
  constexpr int TR = TM + TN;        // staged rows per K-tile (256)
  constexpr int WCOLS = 4;           // 8 waves: 2 rows x 4 cols
  constexpr int WN = TN / WCOLS;     // 32
  constexpr int NJ = WN / 16;        // 2
  constexpr int MT = MPAD / TM;      // M tiles
  __shared__ __align__(16) u16 S0[TR * 64];
  __shared__ __align__(16) u16 S1[TR * 64];
  const int tid = threadIdx.x;
  const int wave = tid >> 6, lane = tid & 63;

  // bijective XCD-chunked swizzle over col-fastest linear id (m204)
  const int nwg = tiles_n * MT;
  const int orig = blockIdx.x + blockIdx.y * tiles_n;
  const int q = nwg >> 3, r8 = nwg & 7;
  const int xcd = orig & 7, idx = orig >> 3;
  const int wg = (xcd < r8 ? xcd * (q + 1) : r8 * (q + 1) + (xcd - r8) * q) + idx;
  const int tm = (wg / tiles_n) * TM;
  const int tn = (wg % tiles_n) * TN;

  const int wr = (wave / WCOLS) * 64;
  const int wc = (wave % WCOLS) * WN;
  const int fr = lane & 15, fq = lane >> 4;
  const int sr8 = lane >> 3;         // row within 8-row wave chunk
  const int sslot = lane & 7;        // 16B slot within 128B row
  f32x4 acc[4][NJ] = {};

  const int nsteps = K >> 6;          // BK=64; K % 64 == 0 in all uses

// linear coalesced global loads: lanes 0..7 sweep one 128B row
#define GLOADV(r, kkx)                                                        \
  {                                                                           \
    const int kk_ = (kkx);                                                    \
    _Pragma("unroll")                                                         \
    for (int c = 0; c < 4; ++c) {                                             \
      const int row_ = c * 64 + wave * 8 + sr8;                               \
      if (c < TM / 64) {                                                      \
        r[c] = (kk_ < ksplit)                                                 \
            ? *(const u16x8*)&A0[(size_t)(tm + row_) * lda0 + kk_ + sslot * 8]\
            : *(const u16x8*)&A1[(size_t)(tm + row_) * lda1 + (kk_ - ksplit) + sslot * 8]; \
      } else {                                                                \
        r[c] = *(const u16x8*)&B[(size_t)(tn + row_ - TM) * (size_t)K + kk_ + sslot * 8];  \
      }                                                                       \
    }                                                                         \
  }

// swizzled LDS write: phys slot = sslot ^ (row&7); row&7 == sr8
#define DSWRITE(Sw, r)                                                        \
  {                                                                           \
    _Pragma("unroll")                                                         \
    for (int c = 0; c < 4; ++c) {                                             \
      const int row_ = c * 64 + wave * 8 + sr8;                               \
      *(u16x8*)&Sw[row_ * 64 + ((sslot ^ sr8) << 3)] = r[c];                  \
    }                                                                         \
  }

// one phase; wset holds raw tile t+1 (to write), lset receives tile t+2
#define PHASE(tx, Sr, Sw, wset, lset)                                         \
  {                                                                           \
    const int t_ = (tx);                                                      \
    __builtin_amdgcn_s_barrier();                                             \
    __builtin_amdgcn_sched_barrier(0);                                        \
    short8 af[4][2], bfr[2][NJ];                                              \
    _Pragma("unroll")                                                         \
    for (int i = 0; i < 4; ++i) {                                             \
      const int r_ = wr + i * 16 + fr;                                        \
      _Pragma("unroll")                                                       \
      for (int kc = 0; kc < 2; ++kc)                                          \
        af[i][kc] = *(const short8*)&Sr[r_ * 64 + ((((kc << 2) | fq) ^ (r_ & 7)) << 3)]; \
    }                                                                         \
    _Pragma("unroll")                                                         \
    for (int j = 0; j < NJ; ++j) {                                            \
      const int r_ = TM + wc + j * 16 + fr;                                   \
      _Pragma("unroll")                                                       \
      for (int kc = 0; kc < 2; ++kc)                                          \
        bfr[kc][j] = *(const short8*)&Sr[r_ * 64 + ((((kc << 2) | fq) ^ (r_ & 7)) << 3)]; \
    }                                                                         \
    __builtin_amdgcn_sched_barrier(0);                                        \
    if (t_ + 2 < nsteps) GLOADV(lset, (t_ + 2) << 6);                         \
    __builtin_amdgcn_sched_barrier(0);                                        \
    if (t_ + 1 < nsteps) {                                                    \
      if (t_ + 2 < nsteps) {                                                  \
        asm volatile("s_waitcnt vmcnt(4)" ::: "memory");                      \
      } else {                                                                \
        asm volatile("s_waitcnt vmcnt(0)" ::: "memory");                      \
      }                                                                       \
      DSWRITE(Sw, wset);                                                      \
    }                                                                         \
    asm volatile("s_waitcnt lgkmcnt(0)" ::: "memory");                        \
    __builtin_amdgcn_sched_barrier(0);                                        \
    __builtin_amdgcn_s_setprio(1);                                            \
    _Pragma("unroll")                                                         \
    for (int kc = 0; kc < 2; ++kc)                                            \
      _Pragma("unroll")                                                       \
      for (int i = 0; i < 4; ++i)                                             \
        _Pragma("unroll")                                                     \
        for (int j = 0; j < NJ; ++j)                                          \
          acc[i][j] = __builtin_amdgcn_mfma_f32_16x16x32_bf16(                \
              __builtin_bit_cast(bf16x8, af[i][kc]),                          \
              __builtin_bit_cast(bf16x8, bfr[kc][j]),                         \
              acc[i][j], 0, 0, 0);                                            \
    __builtin_amdgcn_s_setprio(0);                                            \
    __builtin_amdgcn_sched_barrier(0);                                        \
  }

  u16x8 rA[4], rB[4];
  GLOADV(rA, 0);                      // tile 0
  asm volatile("s_waitcnt vmcnt(0)" ::: "memory");
  DSWRITE(S0, rA);
  GLOADV(rB, 64);                     // tile 1 (nsteps >= 8 always)
  asm volatile("s_waitcnt lgkmcnt(0)" ::: "memory");  // S0 writes retired

  for (int base = 0; base < nsteps; base += 2) {
    PHASE(base, S0, S1, rB, rA);                       // write t+1 (rB), load t+2 -> rA
    if (base + 1 < nsteps)                             // K=960 -> nsteps=15 is ODD
      PHASE(base + 1, S1, S0, rA, rB);                 // write t+2 (rA), load t+3 -> rB
  }
#undef PHASE
#undef DSWRITE
#undef GLOADV

  // C/D layout: col=lane&15, row=(lane>>4)*4+reg (m89/m91 verified)
  const int cr = fq * 4, cc = fr;
#pragma unroll
  for (int i = 0; i < 4; ++i)
#pragma unroll
    for (int j = 0; j < NJ; ++j) {
      const int col = tn + wc + j * 16 + cc;
      const float bv = (col < nbias) ? bias[col] : 0.f;
#pragma unroll
      for (int r = 0; r < 4; ++r) {
        const int row = tm + wr + i * 16 + cr + r;
        float v = acc[i][j][r] + bv;
        if (act) v = fmaxf(v, 0.f);
        Cb[(size_t)row * ldcb + col] = f2bf(v);
      }
    }
}

// ---------------- segment max, XCD feature-sliced ----------------
// Feature dim split into 8 slices of CW; slice c pinned to XCD c via
// blockIdx.x & 7. Per-XCD working set MPAD*CW*2B = 2.6MB/1.3MB < 4MB L2.
// relu'd bf16 >= 0: u16 compare == float compare; 0 == empty-segment fill.
template<int CW>
__global__ __launch_bounds__(256) void aggregate_xcd(
    const u16* __restrict__ m, int ldm, const int* __restrict__ roff,
    const int* __restrict__ esrc, u16* __restrict__ neigh, int ldn) {
  constexpr int TPN = CW / 8;          // threads per node
  constexpr int NPB = 256 / TPN;       // nodes per block
  const int chunk = blockIdx.x & 7;
  const int node = (blockIdx.x >> 3) * NPB + threadIdx.x / TPN;
  if (node >= NN) return;
  const int fi = chunk * CW + (threadIdx.x % TPN) * 8;
  const int beg = roff[node], end = roff[node + 1];
  u16x8 a;
#pragma unroll
  for (int i = 0; i < 8; ++i) a[i] = 0;
  for (int e = beg; e < end; ++e) {
    const u16* row = m + (size_t)esrc[e] * ldm;
    u16x8 v = *(const u16x8*)(row + fi);
#pragma unroll
    for (int i = 0; i < 8; ++i) a[i] = (v[i] > a[i]) ? v[i] : a[i];
  }
  *(u16x8*)(neigh + (size_t)node * ldn + fi) = a;
}

// ---------------- layer 2 output: sigmoid(x2 . Ws2 + neigh2 . Wn2 + b2) ----------------
__global__ __launch_bounds__(256) void final_out(
    const u16* __restrict__ x, const u16* __restrict__ neigh,
    const float* __restrict__ ws, const float* __restrict__ wn,
    const float* __restrict__ b, float* __restrict__ out) {
  const int wave = threadIdx.x >> 6, lane = threadIdx.x & 63;
  const int n = blockIdx.x * 4 + wave;
  if (n >= NN) return;
  const int f = lane * 8;
  const u16* xr = x + (size_t)n * 512 + f;
  const u16* nr = neigh + (size_t)n * 512 + f;
  float s = 0.f;
#pragma unroll
  for (int i = 0; i < 8; ++i)
    s += bf2f(xr[i]) * ws[f + i] + bf2f(nr[i]) * wn[f + i];
#pragma unroll
  for (int o = 32; o > 0; o >>= 1) s += __shfl_xor(s, o);
  if (lane == 0) out[n] = 1.f / (1.f + expf(-(s + b[0])));
}

extern "C" void kernel_launch(void* const* d_in, const int* in_sizes, int n_in,
                              void* d_out, int out_size, void* d_ws, size_t ws_size,
                              hipStream_t stream) {
  const float* h   = (const float*)d_in[0];
  const int*   src = (const int*)d_in[1];
  const int*   dst = (const int*)d_in[2];
  const float* Wp0 = (const float*)d_in[3];
  const float* bp0 = (const float*)d_in[4];
  const float* Ws0 = (const float*)d_in[5];
  const float* Wn0 = (const float*)d_in[6];
  const float* b0  = (const float*)d_in[7];
  const float* Wp1 = (const float*)d_in[8];
  const float* bp1 = (const float*)d_in[9];
  const float* Ws1 = (const float*)d_in[10];
  const float* Wn1 = (const float*)d_in[11];
  const float* b1  = (const float*)d_in[12];
  const float* Wp2 = (const float*)d_in[13];
  const float* bp2 = (const float*)d_in[14];
  const float* Ws2 = (const float*)d_in[15];
  const float* Wn2 = (const float*)d_in[16];
  const float* b2  = (const float*)d_in[17];
  float* out = (float*)d_out;

  char* ws = (char*)d_ws;
  size_t off = 0;
  auto alloc = [&](size_t n) { char* p = ws + off; off = (off + n + 255) & ~(size_t)255; return p; };
  u16* hbf   = (u16*)alloc((size_t)MPAD * 960 * 2);
  u16* x1    = (u16*)alloc((size_t)MPAD * 512 * 2);
  u16* x2    = (u16*)alloc((size_t)MPAD * 512 * 2);
  u16* mbuf  = (u16*)alloc((size_t)MPAD * 1024 * 2);
  u16* nbuf  = (u16*)alloc((size_t)MPAD * 1024 * 2);
  u16* WpT0  = (u16*)alloc((size_t)1024 * 960 * 2);   // [1024 cols][K=960]
  u16* Bcat0 = (u16*)alloc((size_t)512 * 1920 * 2);   // [512][Ws0(960) ; Wn0(960)]
  u16* WpT1  = (u16*)alloc((size_t)512 * 512 * 2);
  u16* Bcat1 = (u16*)alloc((size_t)512 * 1024 * 2);   // [512][Ws1(512) ; Wn1(512)]
  u16* WpT2  = (u16*)alloc((size_t)512 * 512 * 2);
  int* deg   = (int*)alloc(NN * 4);
  int* roff  = (int*)alloc((NN + 1) * 4);
  int* curp  = (int*)alloc(NN * 4);
  int* esrc  = (int*)alloc(NE * 4);

  hipMemsetAsync(deg, 0, NN * 4, stream);
  deg_count<<<NE / 256, 256, 0, stream>>>(dst, deg);
  scan_off<<<1, 256, 0, stream>>>(deg, roff, curp);
  fill_csr<<<NE / 256, 256, 0, stream>>>(src, dst, curp, esrc);
  convert_h<<<(MPAD * 960 / 4) / 256, 256, 0, stream>>>(h, hbf);

  WPack wp;
  wp.d[0] = {Wp0, WpT0,  960, 960, 1024,  960,   0};
  wp.d[1] = {Ws0, Bcat0, 960, 512,  512, 1920,   0};
  wp.d[2] = {Wn0, Bcat0, 960, 512,  512, 1920, 960};
  wp.d[3] = {Wp1, WpT1,  512, 512,  512,  512,   0};
  wp.d[4] = {Ws1, Bcat1, 512, 512,  512, 1024,   0};
  wp.d[5] = {Wn1, Bcat1, 512, 512,  512, 1024, 512};
  wp.d[6] = {Wp2, WpT2,  512, 512,  512,  512,   0};
  transpose_all<<<dim3(32, 30, 7), 256, 0, stream>>>(wp);

  // ---- layer 0 (960 -> 512) ----
  // G1: m0 = relu(hbf @ Wp0 + bp0)  [N=1024 padded, 960 real]
  gemm3<128, 128><<<dim3(8, 79), 512, 0, stream>>>(
      hbf, 960, hbf, 960, 960, WpT0, bp0, 960, mbuf, 1024, 960, 1, 8);
  aggregate_xcd<128><<<5000, 256, 0, stream>>>(mbuf, 1024, roff, esrc, nbuf, 1024);
  // G2: x1 = relu([hbf | nbuf] @ [Ws0;Wn0] + b0)  K = 1920
  gemm3<128, 128><<<dim3(4, 79), 512, 0, stream>>>(
      hbf, 960, nbuf, 1024, 960, Bcat0, b0, 512, x1, 512, 1920, 1, 4);

  // ---- layer 1 (512 -> 512) ----
  gemm3<128, 128><<<dim3(4, 79), 512, 0, stream>>>(
      x1, 512, x1, 512, 512, WpT1, bp1, 512, mbuf, 512, 512, 1, 4);
  aggregate_xcd<64><<<2504, 256, 0, stream>>>(mbuf, 512, roff, esrc, nbuf, 512);
  gemm3<128, 128><<<dim3(4, 79), 512, 0, stream>>>(
      x1, 512, nbuf, 512, 512, Bcat1, b1, 512, x2, 512, 1024, 1, 4);

  // ---- layer 2 (512 -> 1) ----
  gemm3<128, 128><<<dim3(4, 79), 512, 0, stream>>>(
      x2, 512, x2, 512, 512, WpT2, bp2, 512, mbuf, 512, 512, 1, 4);
  aggregate_xcd<64><<<2504, 256, 0, stream>>>(mbuf, 512, roff, esrc, nbuf, 512);
  final_out<<<2500, 256, 0, stream>>>(x2, nbuf, Ws2, Wn2, b2, out);
}

// Round 10
// 308.014 us; speedup vs baseline: 1.3760x; 1.0918x over previous
//
#include <hip/hip_runtime.h>
#include <stdint.h>

#define NN 10000
#define NE 160000
#define MPAD 10112   // 79 * 128 = 158 * 64
#define MTILES 79

typedef unsigned short u16;
typedef float f32x4 __attribute__((ext_vector_type(4)));
typedef short short8 __attribute__((ext_vector_type(8)));
typedef __bf16 bf16x8 __attribute__((ext_vector_type(8)));
typedef unsigned short u16x4 __attribute__((ext_vector_type(4)));
typedef unsigned short u16x8 __attribute__((ext_vector_type(8)));

__device__ __forceinline__ float bf2f(u16 u) {
  union { unsigned u; float f; } c; c.u = ((unsigned)u) << 16; return c.f;
}
__device__ __forceinline__ u16 f2bf(float f) {
  union { float f; unsigned u; } c; c.f = f;
  return (u16)((c.u + 0x7FFFu + ((c.u >> 16) & 1u)) >> 16);
}

__device__ __forceinline__ void gld_lds16(void* lds, const void* g) {
  __builtin_amdgcn_global_load_lds(
      (const unsigned int __attribute__((address_space(1)))*)g,
      (unsigned int __attribute__((address_space(3)))*)lds, 16, 0, 0);
}

// ---------------- CSR build ----------------
__global__ __launch_bounds__(256) void deg_count(const int* __restrict__ dst, int* __restrict__ deg) {
  int e = blockIdx.x * 256 + threadIdx.x;
  if (e < NE) atomicAdd(&deg[dst[e]], 1);
}

__global__ __launch_bounds__(256) void scan_off(const int* __restrict__ deg,
                                                int* __restrict__ roff, int* __restrict__ cur) {
  __shared__ int part[256];
  const int t = threadIdx.x;
  const int CH = 40;
  int s = 0;
  for (int i = 0; i < CH; ++i) { int idx = t * CH + i; if (idx < NN) s += deg[idx]; }
  part[t] = s; __syncthreads();
  for (int off = 1; off < 256; off <<= 1) {
    int v = (t >= off) ? part[t - off] : 0;
    __syncthreads(); part[t] += v; __syncthreads();
  }
  int run = (t == 0) ? 0 : part[t - 1];
  for (int i = 0; i < CH; ++i) {
    int idx = t * CH + i;
    if (idx < NN) { roff[idx] = run; cur[idx] = run; run += deg[idx]; }
  }
  if (t == 255) roff[NN] = NE;
}

__global__ __launch_bounds__(256) void fill_csr(const int* __restrict__ src, const int* __restrict__ dst,
                                                int* __restrict__ cur, int* __restrict__ esrc) {
  int e = blockIdx.x * 256 + threadIdx.x;
  if (e < NE) {
    int p = atomicAdd(&cur[dst[e]], 1);
    esrc[p] = src[e];
  }
}

// ---------------- conversions ----------------
__global__ __launch_bounds__(256) void convert_h(const float* __restrict__ h, u16* __restrict__ hbf) {
  const size_t i = (size_t)(blockIdx.x * 256 + threadIdx.x) * 4;
  if (i >= (size_t)MPAD * 960) return;
  u16x4 o;
  if (i < (size_t)NN * 960) {
    float4 v = *(const float4*)(h + i);
    o[0] = f2bf(v.x); o[1] = f2bf(v.y); o[2] = f2bf(v.z); o[3] = f2bf(v.w);
  } else {
    o[0] = 0; o[1] = 0; o[2] = 0; o[3] = 0;
  }
  *(u16x4*)(hbf + i) = o;
}

// weight transposes, K-concat capable: out[c*ldo + koff + r] = bf16(in[r][c])
struct WDesc { const float* in; u16* out; int R, C, Cpad, ldo, koff; };
struct WPack { WDesc d[7]; };

__global__ __launch_bounds__(256) void transpose_all(WPack p) {
  const WDesc w = p.d[blockIdx.z];
  const int cb = blockIdx.x * 32, rb = blockIdx.y * 32;
  if (cb >= w.Cpad || rb >= w.R) return;
  __shared__ float tile[32][33];
  const int tx = threadIdx.x & 31, ty = threadIdx.x >> 5;
  for (int i = ty; i < 32; i += 8) {
    int r = rb + i, c = cb + tx;
    tile[i][tx] = (r < w.R && c < w.C) ? w.in[(size_t)r * w.C + c] : 0.f;
  }
  __syncthreads();
  for (int i = ty; i < 32; i += 8) {
    int c = cb + i, r = rb + tx;
    if (c < w.Cpad && r < w.R) w.out[(size_t)c * w.ldo + w.koff + r] = f2bf(tile[tx][i]);
  }
}

// ---------------- GEMM: Cb = act(([A0|A1]) @ B^T + bias) ----------------
// MODEL (r0-r9): per-CU staging rate ~= 10 B/cy x co-resident blocks, cap
// ~22; staged bytes ~ (1/TM+1/TN); the product is FLAT across all pure
// configs (r0/r2/r3/r5 all ~41us for G2). r9 (clean reg-staging, no spill)
// measured the reg-path at ~12.9 B/cy/block - a second, INDEPENDENT path.
// THIS VERSION: dual-path staging. A-half (16KB/phase, rows 0..TM) stays on
// global_load_lds DMA (pre-swizzled global source, r5-exact). B-half
// (16KB/phase, rows TM..TM+TN) moves to reg-path: global_load_dwordx4
// (linear) -> ds_write_b128 (swizzled addr), 2 instr/wave, bE/bO parity
// sets (+16 VGPR -> ~120 total, fits 128 @ 4 waves/EU, 2 blocks/CU kept).
// If the engines drain in parallel, phase ~= max(16KB/10B/cy, rest) ~1800cy
// vs 3343 measured.
// Phase t (NSTG=2, Sr=S[t&1] read + gets A(t+2); So=other, gets B(t+1)):
//   vmcnt(4|0)       // A-DMA(t) landed (newer: B-gl(t+1) 2 + A-DMA(t+1) 2)
//   barrier1         // tile t fully visible (B(t) written phase t-1)
//   ds_read tile t
//   B-gl(t+2) -> bL  (2 x dwordx4, linear)
//   vmcnt(4|2)       // B-gl(t+1) landed (newer: A-DMA(t+1) 2 [+ B-gl(t+2) 2])
//   ds_write bW -> So B-rows   (disjoint from So's in-flight A-DMA rows)
//   lgkmcnt(0)       // frags in regs + B-writes retired
//   barrier2         // Sr readers sealed
//   A-DMA(t+2) -> Sr A-rows
//   MFMA x16
// Prologue establishes the same invariants with vmcnt(0). Odd-nsteps tail
// guard kept (G1 K=960 -> 15). PRE-COMMIT: if G2 >= ~40us with clean
// counters, the ~22 B/cy/CU cap is shared (L2-return) -> revert to r5.
template<int TM, int TN, int MINW>
__global__ __launch_bounds__(512, MINW) void gemm3(
    const u16* __restrict__ A0, int lda0,
    const u16* __restrict__ A1, int lda1, int ksplit,
    const u16* __restrict__ B,
    const float* __restrict__ bias, int nbias,
    u16* __restrict__ Cb, int ldcb,
    int K, int act, int tiles_n) {
  constexpr int TR = TM + TN;        // 256 rows per K-tile
  constexpr int WCOLS = 4;           // 8 waves: 2 rows x 4 cols
  constexpr int WN = TN / WCOLS;     // 32
  constexpr int NJ = WN / 16;        // 2
  constexpr int MT = MPAD / TM;      // M tiles
  __shared__ __align__(16) u16 S0[TR * 64];
  __shared__ __align__(16) u16 S1[TR * 64];
  const int tid = threadIdx.x;
  const int wave = tid >> 6, lane = tid & 63;

  // bijective XCD-chunked swizzle over col-fastest linear id (m204)
  const int nwg = tiles_n * MT;
  const int orig = blockIdx.x + blockIdx.y * tiles_n;
  const int q = nwg >> 3, r8 = nwg & 7;
  const int xcd = orig & 7, idx = orig >> 3;
  const int wg = (xcd < r8 ? xcd * (q + 1) : r8 * (q + 1) + (xcd - r8) * q) + idx;
  const int tm = (wg / tiles_n) * TM;
  const int tn = (wg % tiles_n) * TN;

  const int wr = (wave / WCOLS) * 64;
  const int wc = (wave % WCOLS) * WN;
  const int fr = lane & 15, fq = lane >> 4;
  const int sr8 = lane >> 3;         // row within 8-row wave chunk (== row&7)
  const int sslot = lane & 7;        // 16B slot within 128B row
  f32x4 acc[4][NJ] = {};

  const int nsteps = K >> 6;          // BK=64; K % 64 == 0 in all uses; nsteps >= 8

// A rows 0..TM-1 via global_load_lds DMA, pre-swizzled global source (r5-exact)
#define DMAA(Sw, kkx)                                                         \
  {                                                                           \
    const int kk_ = (kkx);                                                    \
    _Pragma("unroll")                                                         \
    for (int c = 0; c < 2; ++c) {                                             \
      const int row_ = c * 64 + wave * 8 + sr8;                               \
      const int gs_ = (sslot ^ sr8) * 8;                                      \
      const void* g_ = (kk_ < ksplit)                                         \
          ? (const void*)&A0[(size_t)(tm + row_) * lda0 + kk_ + gs_]          \
          : (const void*)&A1[(size_t)(tm + row_) * lda1 + (kk_ - ksplit) + gs_]; \
      gld_lds16(&Sw[(c * 64 + wave * 8) * 64], g_);                           \
    }                                                                         \
  }

// B rows (cols of C) via linear coalesced VMEM loads -> regs
#define GLOADB(r, kkx)                                                        \
  {                                                                           \
    const int kk_ = (kkx);                                                    \
    _Pragma("unroll")                                                         \
    for (int c = 0; c < 2; ++c) {                                             \
      const int row_ = c * 64 + wave * 8 + sr8;                               \
      r[c] = *(const u16x8*)&B[(size_t)(tn + row_) * (size_t)K + kk_ + sslot * 8]; \
    }                                                                         \
  }

// swizzled LDS write of B regs into rows TM..TM+TN-1
#define DSWRITEB(Sw, r)                                                       \
  {                                                                           \
    _Pragma("unroll")                                                         \
    for (int c = 0; c < 2; ++c) {                                             \
      const int row_ = TM + c * 64 + wave * 8 + sr8;                          \
      *(u16x8*)&Sw[row_ * 64 + ((sslot ^ sr8) << 3)] = r[c];                  \
    }                                                                         \
  }

#define PHASE(tx, Sr, So, bW, bL)                                             \
  {                                                                           \
    const int t_ = (tx);                                                      \
    if (t_ + 1 < nsteps) {                                                    \
      asm volatile("s_waitcnt vmcnt(4)" ::: "memory");  /* A-DMA(t) landed */ \
    } else {                                                                  \
      asm volatile("s_waitcnt vmcnt(0)" ::: "memory");                        \
    }                                                                         \
    __builtin_amdgcn_s_barrier();     /* tile t visible; So B-rows sealed */  \
    __builtin_amdgcn_sched_barrier(0);                                        \
    short8 af[4][2], bfr[2][NJ];                                              \
    _Pragma("unroll")                                                         \
    for (int i = 0; i < 4; ++i) {                                             \
      const int r_ = wr + i * 16 + fr;                                        \
      _Pragma("unroll")                                                       \
      for (int kc = 0; kc < 2; ++kc)                                          \
        af[i][kc] = *(const short8*)&Sr[r_ * 64 + ((((kc << 2) | fq) ^ (r_ & 7)) << 3)]; \
    }                                                                         \
    _Pragma("unroll")                                                         \
    for (int j = 0; j < NJ; ++j) {                                            \
      const int r_ = TM + wc + j * 16 + fr;                                   \
      _Pragma("unroll")                                                       \
      for (int kc = 0; kc < 2; ++kc)                                          \
        bfr[kc][j] = *(const short8*)&Sr[r_ * 64 + ((((kc << 2) | fq) ^ (r_ & 7)) << 3)]; \
    }                                                                         \
    __builtin_amdgcn_sched_barrier(0);                                        \
    if (t_ + 2 < nsteps) GLOADB(bL, (t_ + 2) << 6);                           \
    __builtin_amdgcn_sched_barrier(0);                                        \
    if (t_ + 1 < nsteps) {                                                    \
      if (t_ + 2 < nsteps) {                                                  \
        asm volatile("s_waitcnt vmcnt(4)" ::: "memory"); /* B-gl(t+1) in */   \
      } else {                                                                \
        asm volatile("s_waitcnt vmcnt(2)" ::: "memory");                      \
      }                                                                       \
      DSWRITEB(So, bW);                                                       \
    }                                                                         \
    asm volatile("s_waitcnt lgkmcnt(0)" ::: "memory"); /* frags + B-writes */ \
    __builtin_amdgcn_sched_barrier(0);                                        \
    __builtin_amdgcn_s_barrier();     /* Sr readers sealed */                 \
    if (t_ + 2 < nsteps) DMAA(Sr, (t_ + 2) << 6);                             \
    __builtin_amdgcn_s_setprio(1);                                            \
    _Pragma("unroll")                                                         \
    for (int kc = 0; kc < 2; ++kc)                                            \
      _Pragma("unroll")                                                       \
      for (int i = 0; i < 4; ++i)                                             \
        _Pragma("unroll")                                                     \
        for (int j = 0; j < NJ; ++j)                                          \
          acc[i][j] = __builtin_amdgcn_mfma_f32_16x16x32_bf16(                \
              __builtin_bit_cast(bf16x8, af[i][kc]),                          \
              __builtin_bit_cast(bf16x8, bfr[kc][j]),                         \
              acc[i][j], 0, 0, 0);                                            \
    __builtin_amdgcn_s_setprio(0);                                            \
    __builtin_amdgcn_sched_barrier(0);                                        \
  }

  u16x8 bE[2], bO[2];
  DMAA(S0, 0);                        // A(0) in flight
  GLOADB(bE, 0);                      // B(0) -> regs
  asm volatile("s_waitcnt vmcnt(0)" ::: "memory");
  DSWRITEB(S0, bE);                   // B(0) -> S0
  GLOADB(bO, 64);                     // B(1) -> regs (nsteps >= 8)
  DMAA(S1, 64);                       // A(1) in flight
  asm volatile("s_waitcnt lgkmcnt(0)" ::: "memory");  // B(0) writes retired

  for (int base = 0; base < nsteps; base += 2) {
    PHASE(base, S0, S1, bO, bE);      // write B(t+1)=bO -> S1, load B(t+2) -> bE
    if (base + 1 < nsteps)            // G1 K=960 -> nsteps=15 is ODD
      PHASE(base + 1, S1, S0, bE, bO);
  }
#undef PHASE
#undef DSWRITEB
#undef GLOADB
#undef DMAA

  // C/D layout: col=lane&15, row=(lane>>4)*4+reg (m89/m91 verified)
  const int cr = fq * 4, cc = fr;
#pragma unroll
  for (int i = 0; i < 4; ++i)
#pragma unroll
    for (int j = 0; j < NJ; ++j) {
      const int col = tn + wc + j * 16 + cc;
      const float bv = (col < nbias) ? bias[col] : 0.f;
#pragma unroll
      for (int r = 0; r < 4; ++r) {
        const int row = tm + wr + i * 16 + cr + r;
        float v = acc[i][j][r] + bv;
        if (act) v = fmaxf(v, 0.f);
        Cb[(size_t)row * ldcb + col] = f2bf(v);
      }
    }
}

// ---------------- segment max, XCD feature-sliced ----------------
// Feature dim split into 8 slices of CW; slice c pinned to XCD c via
// blockIdx.x & 7. Per-XCD working set MPAD*CW*2B = 2.6MB/1.3MB < 4MB L2.
// relu'd bf16 >= 0: u16 compare == float compare; 0 == empty-segment fill.
template<int CW>
__global__ __launch_bounds__(256) void aggregate_xcd(
    const u16* __restrict__ m, int ldm, const int* __restrict__ roff,
    const int* __restrict__ esrc, u16* __restrict__ neigh, int ldn) {
  constexpr int TPN = CW / 8;          // threads per node
  constexpr int NPB = 256 / TPN;       // nodes per block
  const int chunk = blockIdx.x & 7;
  const int node = (blockIdx.x >> 3) * NPB + threadIdx.x / TPN;
  if (node >= NN) return;
  const int fi = chunk * CW + (threadIdx.x % TPN) * 8;
  const int beg = roff[node], end = roff[node + 1];
  u16x8 a;
#pragma unroll
  for (int i = 0; i < 8; ++i) a[i] = 0;
  for (int e = beg; e < end; ++e) {
    const u16* row = m + (size_t)esrc[e] * ldm;
    u16x8 v = *(const u16x8*)(row + fi);
#pragma unroll
    for (int i = 0; i < 8; ++i) a[i] = (v[i] > a[i]) ? v[i] : a[i];
  }
  *(u16x8*)(neigh + (size_t)node * ldn + fi) = a;
}

// ---------------- layer 2 output: sigmoid(x2 . Ws2 + neigh2 . Wn2 + b2) ----------------
__global__ __launch_bounds__(256) void final_out(
    const u16* __restrict__ x, const u16* __restrict__ neigh,
    const float* __restrict__ ws, const float* __restrict__ wn,
    const float* __restrict__ b, float* __restrict__ out) {
  const int wave = threadIdx.x >> 6, lane = threadIdx.x & 63;
  const int n = blockIdx.x * 4 + wave;
  if (n >= NN) return;
  const int f = lane * 8;
  const u16* xr = x + (size_t)n * 512 + f;
  const u16* nr = neigh + (size_t)n * 512 + f;
  float s = 0.f;
#pragma unroll
  for (int i = 0; i < 8; ++i)
    s += bf2f(xr[i]) * ws[f + i] + bf2f(nr[i]) * wn[f + i];
#pragma unroll
  for (int o = 32; o > 0; o >>= 1) s += __shfl_xor(s, o);
  if (lane == 0) out[n] = 1.f / (1.f + expf(-(s + b[0])));
}

extern "C" void kernel_launch(void* const* d_in, const int* in_sizes, int n_in,
                              void* d_out, int out_size, void* d_ws, size_t ws_size,
                              hipStream_t stream) {
  const float* h   = (const float*)d_in[0];
  const int*   src = (const int*)d_in[1];
  const int*   dst = (const int*)d_in[2];
  const float* Wp0 = (const float*)d_in[3];
  const float* bp0 = (const float*)d_in[4];
  const float* Ws0 = (const float*)d_in[5];
  const float* Wn0 = (const float*)d_in[6];
  const float* b0  = (const float*)d_in[7];
  const float* Wp1 = (const float*)d_in[8];
  const float* bp1 = (const float*)d_in[9];
  const float* Ws1 = (const float*)d_in[10];
  const float* Wn1 = (const float*)d_in[11];
  const float* b1  = (const float*)d_in[12];
  const float* Wp2 = (const float*)d_in[13];
  const float* bp2 = (const float*)d_in[14];
  const float* Ws2 = (const float*)d_in[15];
  const float* Wn2 = (const float*)d_in[16];
  const float* b2  = (const float*)d_in[17];
  float* out = (float*)d_out;

  char* ws = (char*)d_ws;
  size_t off = 0;
  auto alloc = [&](size_t n) { char* p = ws + off; off = (off + n + 255) & ~(size_t)255; return p; };
  u16* hbf   = (u16*)alloc((size_t)MPAD * 960 * 2);
  u16* x1    = (u16*)alloc((size_t)MPAD * 512 * 2);
  u16* x2    = (u16*)alloc((size_t)MPAD * 512 * 2);
  u16* mbuf  = (u16*)alloc((size_t)MPAD * 1024 * 2);
  u16* nbuf  = (u16*)alloc((size_t)MPAD * 1024 * 2);
  u16* WpT0  = (u16*)alloc((size_t)1024 * 960 * 2);   // [1024 cols][K=960]
  u16* Bcat0 = (u16*)alloc((size_t)512 * 1920 * 2);   // [512][Ws0(960) ; Wn0(960)]
  u16* WpT1  = (u16*)alloc((size_t)512 * 512 * 2);
  u16* Bcat1 = (u16*)alloc((size_t)512 * 1024 * 2);   // [512][Ws1(512) ; Wn1(512)]
  u16* WpT2  = (u16*)alloc((size_t)512 * 512 * 2);
  int* deg   = (int*)alloc(NN * 4);
  int* roff  = (int*)alloc((NN + 1) * 4);
  int* curp  = (int*)alloc(NN * 4);
  int* esrc  = (int*)alloc(NE * 4);

  hipMemsetAsync(deg, 0, NN * 4, stream);
  deg_count<<<NE / 256, 256, 0, stream>>>(dst, deg);
  scan_off<<<1, 256, 0, stream>>>(deg, roff, curp);
  fill_csr<<<NE / 256, 256, 0, stream>>>(src, dst, curp, esrc);
  convert_h<<<(MPAD * 960 / 4) / 256, 256, 0, stream>>>(h, hbf);

  WPack wp;
  wp.d[0] = {Wp0, WpT0,  960, 960, 1024,  960,   0};
  wp.d[1] = {Ws0, Bcat0, 960, 512,  512, 1920,   0};
  wp.d[2] = {Wn0, Bcat0, 960, 512,  512, 1920, 960};
  wp.d[3] = {Wp1, WpT1,  512, 512,  512,  512,   0};
  wp.d[4] = {Ws1, Bcat1, 512, 512,  512, 1024,   0};
  wp.d[5] = {Wn1, Bcat1, 512, 512,  512, 1024, 512};
  wp.d[6] = {Wp2, WpT2,  512, 512,  512,  512,   0};
  transpose_all<<<dim3(32, 30, 7), 256, 0, stream>>>(wp);

  // ---- layer 0 (960 -> 512) ----
  // G1: m0 = relu(hbf @ Wp0 + bp0)  [N=1024 padded, 960 real]
  gemm3<128, 128, 4><<<dim3(8, 79), 512, 0, stream>>>(
      hbf, 960, hbf, 960, 960, WpT0, bp0, 960, mbuf, 1024, 960, 1, 8);
  aggregate_xcd<128><<<5000, 256, 0, stream>>>(mbuf, 1024, roff, esrc, nbuf, 1024);
  // G2: x1 = relu([hbf | nbuf] @ [Ws0;Wn0] + b0)  K = 1920
  gemm3<128, 128, 4><<<dim3(4, 79), 512, 0, stream>>>(
      hbf, 960, nbuf, 1024, 960, Bcat0, b0, 512, x1, 512, 1920, 1, 4);

  // ---- layer 1 (512 -> 512) ----
  gemm3<128, 128, 4><<<dim3(4, 79), 512, 0, stream>>>(
      x1, 512, x1, 512, 512, WpT1, bp1, 512, mbuf, 512, 512, 1, 4);
  aggregate_xcd<64><<<2504, 256, 0, stream>>>(mbuf, 512, roff, esrc, nbuf, 512);
  gemm3<128, 128, 4><<<dim3(4, 79), 512, 0, stream>>>(
      x1, 512, nbuf, 512, 512, Bcat1, b1, 512, x2, 512, 1024, 1, 4);

  // ---- layer 2 (512 -> 1) ----
  gemm3<128, 128, 4><<<dim3(4, 79), 512, 0, stream>>>(
      x2, 512, x2, 512, 512, WpT2, bp2, 512, mbuf, 512, 512, 1, 4);
  aggregate_xcd<64><<<2504, 256, 0, stream>>>(mbuf, 512, roff, esrc, nbuf, 512);
  final_out<<<2500, 256, 0, stream>>>(x2, nbuf, Ws2, Wn2, b2, out);
}

// Round 11
// 270.587 us; speedup vs baseline: 1.5664x; 1.1383x over previous
//
#include <hip/hip_runtime.h>
#include <stdint.h>

#define NN 10000
#define NE 160000
#define MPAD 10112   // 79 * 128 = 158 * 64
#define MTILES 79

typedef unsigned short u16;
typedef float f32x4 __attribute__((ext_vector_type(4)));
typedef short short8 __attribute__((ext_vector_type(8)));
typedef __bf16 bf16x8 __attribute__((ext_vector_type(8)));
typedef unsigned short u16x4 __attribute__((ext_vector_type(4)));
typedef unsigned short u16x8 __attribute__((ext_vector_type(8)));

__device__ __forceinline__ float bf2f(u16 u) {
  union { unsigned u; float f; } c; c.u = ((unsigned)u) << 16; return c.f;
}
__device__ __forceinline__ u16 f2bf(float f) {
  union { float f; unsigned u; } c; c.f = f;
  return (u16)((c.u + 0x7FFFu + ((c.u >> 16) & 1u)) >> 16);
}

__device__ __forceinline__ void gld_lds16(void* lds, const void* g) {
  __builtin_amdgcn_global_load_lds(
      (const unsigned int __attribute__((address_space(1)))*)g,
      (unsigned int __attribute__((address_space(3)))*)lds, 16, 0, 0);
}

// ---------------- CSR build ----------------
__global__ __launch_bounds__(256) void deg_count(const int* __restrict__ dst, int* __restrict__ deg) {
  int e = blockIdx.x * 256 + threadIdx.x;
  if (e < NE) atomicAdd(&deg[dst[e]], 1);
}

__global__ __launch_bounds__(256) void scan_off(const int* __restrict__ deg,
                                                int* __restrict__ roff, int* __restrict__ cur) {
  __shared__ int part[256];
  const int t = threadIdx.x;
  const int CH = 40;
  int s = 0;
  for (int i = 0; i < CH; ++i) { int idx = t * CH + i; if (idx < NN) s += deg[idx]; }
  part[t] = s; __syncthreads();
  for (int off = 1; off < 256; off <<= 1) {
    int v = (t >= off) ? part[t - off] : 0;
    __syncthreads(); part[t] += v; __syncthreads();
  }
  int run = (t == 0) ? 0 : part[t - 1];
  for (int i = 0; i < CH; ++i) {
    int idx = t * CH + i;
    if (idx < NN) { roff[idx] = run; cur[idx] = run; run += deg[idx]; }
  }
  if (t == 255) roff[NN] = NE;
}

__global__ __launch_bounds__(256) void fill_csr(const int* __restrict__ src, const int* __restrict__ dst,
                                                int* __restrict__ cur, int* __restrict__ esrc) {
  int e = blockIdx.x * 256 + threadIdx.x;
  if (e < NE) {
    int p = atomicAdd(&cur[dst[e]], 1);
    esrc[p] = src[e];
  }
}

// ---------------- conversions ----------------
__global__ __launch_bounds__(256) void convert_h(const float* __restrict__ h, u16* __restrict__ hbf) {
  const size_t i = (size_t)(blockIdx.x * 256 + threadIdx.x) * 4;
  if (i >= (size_t)MPAD * 960) return;
  u16x4 o;
  if (i < (size_t)NN * 960) {
    float4 v = *(const float4*)(h + i);
    o[0] = f2bf(v.x); o[1] = f2bf(v.y); o[2] = f2bf(v.z); o[3] = f2bf(v.w);
  } else {
    o[0] = 0; o[1] = 0; o[2] = 0; o[3] = 0;
  }
  *(u16x4*)(hbf + i) = o;
}

// weight transposes, K-concat capable: out[c*ldo + koff + r] = bf16(in[r][c])
struct WDesc { const float* in; u16* out; int R, C, Cpad, ldo, koff; };
struct WPack { WDesc d[7]; };

__global__ __launch_bounds__(256) void transpose_all(WPack p) {
  const WDesc w = p.d[blockIdx.z];
  const int cb = blockIdx.x * 32, rb = blockIdx.y * 32;
  if (cb >= w.Cpad || rb >= w.R) return;
  __shared__ float tile[32][33];
  const int tx = threadIdx.x & 31, ty = threadIdx.x >> 5;
  for (int i = ty; i < 32; i += 8) {
    int r = rb + i, c = cb + tx;
    tile[i][tx] = (r < w.R && c < w.C) ? w.in[(size_t)r * w.C + c] : 0.f;
  }
  __syncthreads();
  for (int i = ty; i < 32; i += 8) {
    int c = cb + i, r = rb + tx;
    if (c < w.Cpad && r < w.R) w.out[(size_t)c * w.ldo + w.koff + r] = f2bf(tile[tx][i]);
  }
}

// ---------------- GEMM: Cb = act(([A0|A1]) @ B^T + bias) ----------------
// LAW (rounds 0-10): gemm time == ONE block's serial chain = nsteps x
// phase_cost, phase_cost ~= staged bytes/phase / ~9.6 B/cy (per-block DMA
// rate; invariant to wave count, pipeline depth; reg-staging/dual-path all
// lost - r6-r10). Chain bytes = K x (TM+TN) x 2B. THIS ROUND: shrink TR
// for the N=512 gemms: TN=64 -> TR=192 (-25% chain), grid 632 blocks
// (2.47/CU), total staged 466MB still under the ~22 B/cy/CU cap. G1 keeps
// TN=128 (TR=192 variant there is cap-bound worse). Pipeline = round-5
// verbatim (passed twice): 8 waves, BK=64, two TR*128B buffers, per phase:
//   vmcnt(NC) [tile t landed; t+1 in flight] ; s_barrier ; ds_read tile t ;
//   lgkmcnt(0) ; s_barrier [all waves' frags in regs] ; stage tile t+2
//   into the same buffer ; MFMA.
// Wave geometry: TN=128 -> 2x4 grid, per-wave 4x2 frags (64-row span);
// TN=64 -> 4x2 grid, per-wave 2x2 frags (32-row span). Staging NC=TR/64
// instrs/lane (4 or 3), rows c*64 + wave*8 + sr8, A if c < NC*TM/TR.
// Swizzle (8x16B slots per 128B row): phys = logical ^ (row&7), same XOR
// on the pre-swizzled global source (rule #21, involution). ksplit%64==0.
// PRE-COMMIT: if G2-class >= 40us, TR-scaling is exhausted -> revert r5.
template<int TM, int TN, int MINW>
__global__ __launch_bounds__(512, MINW) void gemm3(
    const u16* __restrict__ A0, int lda0,
    const u16* __restrict__ A1, int lda1, int ksplit,
    const u16* __restrict__ B,
    const float* __restrict__ bias, int nbias,
    u16* __restrict__ Cb, int ldcb,
    int K, int act, int tiles_n) {
  constexpr int TR = TM + TN;        // staged rows per K-tile (256 or 192)
  constexpr int NC = TR / 64;        // gld instrs per lane per stage (4 or 3)
  constexpr int WCOLS = (TN == 128) ? 4 : 2;
  constexpr int WROWS = 8 / WCOLS;   // 2 or 4
  constexpr int MI = TM / WROWS / 16;  // row frags per wave (4 or 2)
  constexpr int NJ = TN / WCOLS / 16;  // col frags per wave (2)
  constexpr int MT = MPAD / TM;      // M tiles (79)
  __shared__ __align__(16) u16 S0[TR * 64];
  __shared__ __align__(16) u16 S1[TR * 64];
  const int tid = threadIdx.x;
  const int wave = tid >> 6, lane = tid & 63;

  // bijective XCD-chunked swizzle over col-fastest linear id (m204)
  const int nwg = tiles_n * MT;
  const int orig = blockIdx.x + blockIdx.y * tiles_n;
  const int q = nwg >> 3, r8 = nwg & 7;
  const int xcd = orig & 7, idx = orig >> 3;
  const int wg = (xcd < r8 ? xcd * (q + 1) : r8 * (q + 1) + (xcd - r8) * q) + idx;
  const int tm = (wg / tiles_n) * TM;
  const int tn = (wg % tiles_n) * TN;

  const int wr = (wave / WCOLS) * (TM / WROWS);
  const int wc = (wave % WCOLS) * (TN / WCOLS);
  const int fr = lane & 15, fq = lane >> 4;
  const int sr8 = lane >> 3;         // row within 8-row wave chunk (== row&7)
  const int sslot = lane & 7;        // 16B slot within 128B row
  f32x4 acc[MI][NJ] = {};

  auto stage = [&](u16* Sw, int kk) {
#pragma unroll
    for (int c = 0; c < NC; ++c) {
      const int row = c * 64 + wave * 8 + sr8;                // LDS row
      const int gs = (sslot ^ (row & 7)) * 8;                 // pre-swizzled k-slot
      const void* g;
      if (c < NC * TM / TR) {                                 // A rows (row < TM)
        g = (kk < ksplit)
            ? (const void*)&A0[(size_t)(tm + row) * lda0 + kk + gs]
            : (const void*)&A1[(size_t)(tm + row) * lda1 + (kk - ksplit) + gs];
      } else {                                                // B rows
        g = (const void*)&B[(size_t)(tn + row - TM) * (size_t)K + kk + gs];
      }
      gld_lds16(&Sw[(c * 64 + wave * 8) * 64], g);            // wave-uniform base
    }
  };

  const int nsteps = K >> 6;          // BK=64; K % 64 == 0 in all uses
  stage(S0, 0);
  stage(S1, 64);
  for (int base = 0; base < nsteps; base += 2) {
#pragma unroll
    for (int ph = 0; ph < 2; ++ph) {
      const int t = base + ph;
      if (t >= nsteps) break;
      u16* Sr = (ph == 0) ? S0 : S1;   // holds tile t; also gets tile t+2
      if (t + 1 < nsteps) {
        asm volatile("s_waitcnt vmcnt(%0)" :: "i"(NC) : "memory");  // tile t landed
      } else {
        asm volatile("s_waitcnt vmcnt(0)" ::: "memory");
      }
      __builtin_amdgcn_s_barrier();    // all waves' parts of tile t landed
      __builtin_amdgcn_sched_barrier(0);
      short8 af[MI][2], bfr[2][NJ];
#pragma unroll
      for (int i = 0; i < MI; ++i) {
        const int r = wr + i * 16 + fr;
#pragma unroll
        for (int kc = 0; kc < 2; ++kc)
          af[i][kc] = *(const short8*)&Sr[r * 64 + ((((kc << 2) | fq) ^ (r & 7)) << 3)];
      }
#pragma unroll
      for (int j = 0; j < NJ; ++j) {
        const int r = TM + wc + j * 16 + fr;
#pragma unroll
        for (int kc = 0; kc < 2; ++kc)
          bfr[kc][j] = *(const short8*)&Sr[r * 64 + ((((kc << 2) | fq) ^ (r & 7)) << 3)];
      }
      asm volatile("s_waitcnt lgkmcnt(0)" ::: "memory");  // frags in registers
      __builtin_amdgcn_sched_barrier(0);
      __builtin_amdgcn_s_barrier();    // ALL waves done reading Sr -> safe to overwrite
      if (t + 2 < nsteps) stage(Sr, (t + 2) << 6);
      __builtin_amdgcn_s_setprio(1);
#pragma unroll
      for (int kc = 0; kc < 2; ++kc)
#pragma unroll
        for (int i = 0; i < MI; ++i)
#pragma unroll
          for (int j = 0; j < NJ; ++j)
            acc[i][j] = __builtin_amdgcn_mfma_f32_16x16x32_bf16(
                __builtin_bit_cast(bf16x8, af[i][kc]), __builtin_bit_cast(bf16x8, bfr[kc][j]),
                acc[i][j], 0, 0, 0);
      __builtin_amdgcn_s_setprio(0);
      __builtin_amdgcn_sched_barrier(0);
    }
  }

  // C/D layout: col=lane&15, row=(lane>>4)*4+reg (m89/m91 verified)
  const int cr = fq * 4, cc = fr;
#pragma unroll
  for (int i = 0; i < MI; ++i)
#pragma unroll
    for (int j = 0; j < NJ; ++j) {
      const int col = tn + wc + j * 16 + cc;
      const float bv = (col < nbias) ? bias[col] : 0.f;
#pragma unroll
      for (int r = 0; r < 4; ++r) {
        const int row = tm + wr + i * 16 + cr + r;
        float v = acc[i][j][r] + bv;
        if (act) v = fmaxf(v, 0.f);
        Cb[(size_t)row * ldcb + col] = f2bf(v);
      }
    }
}

// ---------------- segment max, XCD feature-sliced ----------------
// Feature dim split into 8 slices of CW; slice c pinned to XCD c via
// blockIdx.x & 7. Per-XCD working set MPAD*CW*2B = 2.6MB/1.3MB < 4MB L2.
// relu'd bf16 >= 0: u16 compare == float compare; 0 == empty-segment fill.
template<int CW>
__global__ __launch_bounds__(256) void aggregate_xcd(
    const u16* __restrict__ m, int ldm, const int* __restrict__ roff,
    const int* __restrict__ esrc, u16* __restrict__ neigh, int ldn) {
  constexpr int TPN = CW / 8;          // threads per node
  constexpr int NPB = 256 / TPN;       // nodes per block
  const int chunk = blockIdx.x & 7;
  const int node = (blockIdx.x >> 3) * NPB + threadIdx.x / TPN;
  if (node >= NN) return;
  const int fi = chunk * CW + (threadIdx.x % TPN) * 8;
  const int beg = roff[node], end = roff[node + 1];
  u16x8 a;
#pragma unroll
  for (int i = 0; i < 8; ++i) a[i] = 0;
  for (int e = beg; e < end; ++e) {
    const u16* row = m + (size_t)esrc[e] * ldm;
    u16x8 v = *(const u16x8*)(row + fi);
#pragma unroll
    for (int i = 0; i < 8; ++i) a[i] = (v[i] > a[i]) ? v[i] : a[i];
  }
  *(u16x8*)(neigh + (size_t)node * ldn + fi) = a;
}

// ---------------- layer 2 output: sigmoid(x2 . Ws2 + neigh2 . Wn2 + b2) ----------------
__global__ __launch_bounds__(256) void final_out(
    const u16* __restrict__ x, const u16* __restrict__ neigh,
    const float* __restrict__ ws, const float* __restrict__ wn,
    const float* __restrict__ b, float* __restrict__ out) {
  const int wave = threadIdx.x >> 6, lane = threadIdx.x & 63;
  const int n = blockIdx.x * 4 + wave;
  if (n >= NN) return;
  const int f = lane * 8;
  const u16* xr = x + (size_t)n * 512 + f;
  const u16* nr = neigh + (size_t)n * 512 + f;
  float s = 0.f;
#pragma unroll
  for (int i = 0; i < 8; ++i)
    s += bf2f(xr[i]) * ws[f + i] + bf2f(nr[i]) * wn[f + i];
#pragma unroll
  for (int o = 32; o > 0; o >>= 1) s += __shfl_xor(s, o);
  if (lane == 0) out[n] = 1.f / (1.f + expf(-(s + b[0])));
}

extern "C" void kernel_launch(void* const* d_in, const int* in_sizes, int n_in,
                              void* d_out, int out_size, void* d_ws, size_t ws_size,
                              hipStream_t stream) {
  const float* h   = (const float*)d_in[0];
  const int*   src = (const int*)d_in[1];
  const int*   dst = (const int*)d_in[2];
  const float* Wp0 = (const float*)d_in[3];
  const float* bp0 = (const float*)d_in[4];
  const float* Ws0 = (const float*)d_in[5];
  const float* Wn0 = (const float*)d_in[6];
  const float* b0  = (const float*)d_in[7];
  const float* Wp1 = (const float*)d_in[8];
  const float* bp1 = (const float*)d_in[9];
  const float* Ws1 = (const float*)d_in[10];
  const float* Wn1 = (const float*)d_in[11];
  const float* b1  = (const float*)d_in[12];
  const float* Wp2 = (const float*)d_in[13];
  const float* bp2 = (const float*)d_in[14];
  const float* Ws2 = (const float*)d_in[15];
  const float* Wn2 = (const float*)d_in[16];
  const float* b2  = (const float*)d_in[17];
  float* out = (float*)d_out;

  char* ws = (char*)d_ws;
  size_t off = 0;
  auto alloc = [&](size_t n) { char* p = ws + off; off = (off + n + 255) & ~(size_t)255; return p; };
  u16* hbf   = (u16*)alloc((size_t)MPAD * 960 * 2);
  u16* x1    = (u16*)alloc((size_t)MPAD * 512 * 2);
  u16* x2    = (u16*)alloc((size_t)MPAD * 512 * 2);
  u16* mbuf  = (u16*)alloc((size_t)MPAD * 1024 * 2);
  u16* nbuf  = (u16*)alloc((size_t)MPAD * 1024 * 2);
  u16* WpT0  = (u16*)alloc((size_t)1024 * 960 * 2);   // [1024 cols][K=960]
  u16* Bcat0 = (u16*)alloc((size_t)512 * 1920 * 2);   // [512][Ws0(960) ; Wn0(960)]
  u16* WpT1  = (u16*)alloc((size_t)512 * 512 * 2);
  u16* Bcat1 = (u16*)alloc((size_t)512 * 1024 * 2);   // [512][Ws1(512) ; Wn1(512)]
  u16* WpT2  = (u16*)alloc((size_t)512 * 512 * 2);
  int* deg   = (int*)alloc(NN * 4);
  int* roff  = (int*)alloc((NN + 1) * 4);
  int* curp  = (int*)alloc(NN * 4);
  int* esrc  = (int*)alloc(NE * 4);

  hipMemsetAsync(deg, 0, NN * 4, stream);
  deg_count<<<NE / 256, 256, 0, stream>>>(dst, deg);
  scan_off<<<1, 256, 0, stream>>>(deg, roff, curp);
  fill_csr<<<NE / 256, 256, 0, stream>>>(src, dst, curp, esrc);
  convert_h<<<(MPAD * 960 / 4) / 256, 256, 0, stream>>>(h, hbf);

  WPack wp;
  wp.d[0] = {Wp0, WpT0,  960, 960, 1024,  960,   0};
  wp.d[1] = {Ws0, Bcat0, 960, 512,  512, 1920,   0};
  wp.d[2] = {Wn0, Bcat0, 960, 512,  512, 1920, 960};
  wp.d[3] = {Wp1, WpT1,  512, 512,  512,  512,   0};
  wp.d[4] = {Ws1, Bcat1, 512, 512,  512, 1024,   0};
  wp.d[5] = {Wn1, Bcat1, 512, 512,  512, 1024, 512};
  wp.d[6] = {Wp2, WpT2,  512, 512,  512,  512,   0};
  transpose_all<<<dim3(32, 30, 7), 256, 0, stream>>>(wp);

  // ---- layer 0 (960 -> 512) ----
  // G1: m0 = relu(hbf @ Wp0 + bp0)  [N=1024 padded, 960 real]
  gemm3<128, 128, 4><<<dim3(8, 79), 512, 0, stream>>>(
      hbf, 960, hbf, 960, 960, WpT0, bp0, 960, mbuf, 1024, 960, 1, 8);
  aggregate_xcd<128><<<5000, 256, 0, stream>>>(mbuf, 1024, roff, esrc, nbuf, 1024);
  // G2: x1 = relu([hbf | nbuf] @ [Ws0;Wn0] + b0)  K = 1920, TN=64 (TR=192)
  gemm3<128, 64, 4><<<dim3(8, 79), 512, 0, stream>>>(
      hbf, 960, nbuf, 1024, 960, Bcat0, b0, 512, x1, 512, 1920, 1, 8);

  // ---- layer 1 (512 -> 512) ----
  gemm3<128, 64, 4><<<dim3(8, 79), 512, 0, stream>>>(
      x1, 512, x1, 512, 512, WpT1, bp1, 512, mbuf, 512, 512, 1, 8);
  aggregate_xcd<64><<<2504, 256, 0, stream>>>(mbuf, 512, roff, esrc, nbuf, 512);
  gemm3<128, 64, 4><<<dim3(8, 79), 512, 0, stream>>>(
      x1, 512, nbuf, 512, 512, Bcat1, b1, 512, x2, 512, 1024, 1, 8);

  // ---- layer 2 (512 -> 1) ----
  gemm3<128, 64, 4><<<dim3(8, 79), 512, 0, stream>>>(
      x2, 512, x2, 512, 512, WpT2, bp2, 512, mbuf, 512, 512, 1, 8);
  aggregate_xcd<64><<<2504, 256, 0, stream>>>(mbuf, 512, roff, esrc, nbuf, 512);
  final_out<<<2500, 256, 0, stream>>>(x2, nbuf, Ws2, Wn2, b2, out);
}

// Round 12
// 250.570 us; speedup vs baseline: 1.6915x; 1.0799x over previous
//
#include <hip/hip_runtime.h>
#include <stdint.h>

#define NN 10000
#define NE 160000
#define MPAD 10112   // 79 * 128 = 158 * 64
#define MTILES 79

typedef unsigned short u16;
typedef float f32x4 __attribute__((ext_vector_type(4)));
typedef short short8 __attribute__((ext_vector_type(8)));
typedef __bf16 bf16x8 __attribute__((ext_vector_type(8)));
typedef unsigned short u16x4 __attribute__((ext_vector_type(4)));
typedef unsigned short u16x8 __attribute__((ext_vector_type(8)));

__device__ __forceinline__ float bf2f(u16 u) {
  union { unsigned u; float f; } c; c.u = ((unsigned)u) << 16; return c.f;
}
__device__ __forceinline__ u16 f2bf(float f) {
  union { float f; unsigned u; } c; c.f = f;
  return (u16)((c.u + 0x7FFFu + ((c.u >> 16) & 1u)) >> 16);
}

__device__ __forceinline__ void gld_lds16(void* lds, const void* g) {
  __builtin_amdgcn_global_load_lds(
      (const unsigned int __attribute__((address_space(1)))*)g,
      (unsigned int __attribute__((address_space(3)))*)lds, 16, 0, 0);
}

// ---------------- CSR build ----------------
__global__ __launch_bounds__(256) void deg_count(const int* __restrict__ dst, int* __restrict__ deg) {
  int e = blockIdx.x * 256 + threadIdx.x;
  if (e < NE) atomicAdd(&deg[dst[e]], 1);
}

__global__ __launch_bounds__(256) void scan_off(const int* __restrict__ deg,
                                                int* __restrict__ roff, int* __restrict__ cur) {
  __shared__ int part[256];
  const int t = threadIdx.x;
  const int CH = 40;
  int s = 0;
  for (int i = 0; i < CH; ++i) { int idx = t * CH + i; if (idx < NN) s += deg[idx]; }
  part[t] = s; __syncthreads();
  for (int off = 1; off < 256; off <<= 1) {
    int v = (t >= off) ? part[t - off] : 0;
    __syncthreads(); part[t] += v; __syncthreads();
  }
  int run = (t == 0) ? 0 : part[t - 1];
  for (int i = 0; i < CH; ++i) {
    int idx = t * CH + i;
    if (idx < NN) { roff[idx] = run; cur[idx] = run; run += deg[idx]; }
  }
  if (t == 255) roff[NN] = NE;
}

__global__ __launch_bounds__(256) void fill_csr(const int* __restrict__ src, const int* __restrict__ dst,
                                                int* __restrict__ cur, int* __restrict__ esrc) {
  int e = blockIdx.x * 256 + threadIdx.x;
  if (e < NE) {
    int p = atomicAdd(&cur[dst[e]], 1);
    esrc[p] = src[e];
  }
}

// ---------------- conversions ----------------
__global__ __launch_bounds__(256) void convert_h(const float* __restrict__ h, u16* __restrict__ hbf) {
  const size_t i = (size_t)(blockIdx.x * 256 + threadIdx.x) * 4;
  if (i >= (size_t)MPAD * 960) return;
  u16x4 o;
  if (i < (size_t)NN * 960) {
    float4 v = *(const float4*)(h + i);
    o[0] = f2bf(v.x); o[1] = f2bf(v.y); o[2] = f2bf(v.z); o[3] = f2bf(v.w);
  } else {
    o[0] = 0; o[1] = 0; o[2] = 0; o[3] = 0;
  }
  *(u16x4*)(hbf + i) = o;
}

// weight transposes, K-concat capable: out[c*ldo + koff + r] = bf16(in[r][c])
struct WDesc { const float* in; u16* out; int R, C, Cpad, ldo, koff; };
struct WPack { WDesc d[7]; };

__global__ __launch_bounds__(256) void transpose_all(WPack p) {
  const WDesc w = p.d[blockIdx.z];
  const int cb = blockIdx.x * 32, rb = blockIdx.y * 32;
  if (cb >= w.Cpad || rb >= w.R) return;
  __shared__ float tile[32][33];
  const int tx = threadIdx.x & 31, ty = threadIdx.x >> 5;
  for (int i = ty; i < 32; i += 8) {
    int r = rb + i, c = cb + tx;
    tile[i][tx] = (r < w.R && c < w.C) ? w.in[(size_t)r * w.C + c] : 0.f;
  }
  __syncthreads();
  for (int i = ty; i < 32; i += 8) {
    int c = cb + i, r = rb + tx;
    if (c < w.Cpad && r < w.R) w.out[(size_t)c * w.ldo + w.koff + r] = f2bf(tile[tx][i]);
  }
}

// ---------------- GEMM: Cb = act(([A0|A1]) @ B^T + bias) ----------------
// FINAL MODEL (rounds 0-11): gemm time == one block's serial phase chain;
// per-CU staging throughput pinned at ~12 B/cy (~7.4 TB/s aggregate) at
// 1.2-2.5 blocks/CU, INVARIANT to: tile shape (r2/r11), BK (r3), pipeline
// depth (r1), wave count (r5: +10% only), staging path (reg-staging r9
// loses; dual-path r10 spills at 4w/EU; B-gather r4 2x loss). The
// byte-x-rate product is flat in every direction. This file = round-5
// config, the measured optimum of the family (251.2us, passed twice):
// 8-WAVE blocks (512 thr), BK=64, two 32KB buffers, per phase:
//   vmcnt(NC) [tile t landed; t+1 in flight] ; s_barrier ; ds_read tile t ;
//   lgkmcnt(0) ; s_barrier [all waves' frags in regs] ; stage tile t+2
//   into the same buffer ; MFMA (16/wave).
// Swizzle (8x16B slots per 128B row): phys = logical ^ (row&7), same XOR
// on the pre-swizzled global source (rule #21, involution). 16 rows ->
// 8 slots x2 = 2-way bank aliasing = free (m136). ksplit%64==0 always.
// Known non-levers (do not retry): NSTG=4, TM=64, TN=64, BK=32-vs-64 at
// fixed structure, reg-staging in any form at <256-reg budget.
template<int TM, int TN, int MINW>
__global__ __launch_bounds__(512, MINW) void gemm3(
    const u16* __restrict__ A0, int lda0,
    const u16* __restrict__ A1, int lda1, int ksplit,
    const u16* __restrict__ B,
    const float* __restrict__ bias, int nbias,
    u16* __restrict__ Cb, int ldcb,
    int K, int act, int tiles_n) {
  constexpr int TR = TM + TN;        // staged rows per K-tile (256)
  constexpr int NC = TR * 128 / (512 * 16);  // gld instrs per lane per stage (4)
  constexpr int WCOLS = 4;           // 8 waves: 2 rows x 4 cols
  constexpr int WN = TN / WCOLS;     // 32
  constexpr int NJ = WN / 16;        // 2
  constexpr int MT = MPAD / TM;      // M tiles
  __shared__ __align__(16) u16 S0[TR * 64];
  __shared__ __align__(16) u16 S1[TR * 64];
  const int tid = threadIdx.x;
  const int wave = tid >> 6, lane = tid & 63;

  // bijective XCD-chunked swizzle over col-fastest linear id (m204)
  const int nwg = tiles_n * MT;
  const int orig = blockIdx.x + blockIdx.y * tiles_n;
  const int q = nwg >> 3, r8 = nwg & 7;
  const int xcd = orig & 7, idx = orig >> 3;
  const int wg = (xcd < r8 ? xcd * (q + 1) : r8 * (q + 1) + (xcd - r8) * q) + idx;
  const int tm = (wg / tiles_n) * TM;
  const int tn = (wg % tiles_n) * TN;

  const int wr = (wave / WCOLS) * 64;
  const int wc = (wave % WCOLS) * WN;
  const int fr = lane & 15, fq = lane >> 4;
  const int sr8 = lane >> 3;         // row within 8-row wave chunk
  const int sslot = lane & 7;        // 16B slot within 128B row
  f32x4 acc[4][NJ] = {};

  auto stage = [&](u16* Sw, int kk) {
#pragma unroll
    for (int c = 0; c < NC; ++c) {
      const int row = c * 64 + wave * 8 + sr8;                // LDS row
      const int gs = (sslot ^ (row & 7)) * 8;                 // pre-swizzled k-slot
      const void* g;
      if (c < NC * TM / TR) {                                 // A rows (row < TM)
        g = (kk < ksplit)
            ? (const void*)&A0[(size_t)(tm + row) * lda0 + kk + gs]
            : (const void*)&A1[(size_t)(tm + row) * lda1 + (kk - ksplit) + gs];
      } else {                                                // B rows
        g = (const void*)&B[(size_t)(tn + row - TM) * (size_t)K + kk + gs];
      }
      gld_lds16(&Sw[(c * 64 + wave * 8) * 64], g);            // wave-uniform base
    }
  };

  const int nsteps = K >> 6;          // BK=64; all K used are multiples of 64
  stage(S0, 0);
  stage(S1, 64);
  for (int base = 0; base < nsteps; base += 2) {
#pragma unroll
    for (int ph = 0; ph < 2; ++ph) {
      const int t = base + ph;
      if (t >= nsteps) break;
      u16* Sr = (ph == 0) ? S0 : S1;   // holds tile t; also gets tile t+2
      if (t + 1 < nsteps) {
        asm volatile("s_waitcnt vmcnt(%0)" :: "i"(NC) : "memory");  // tile t landed
      } else {
        asm volatile("s_waitcnt vmcnt(0)" ::: "memory");
      }
      __builtin_amdgcn_s_barrier();    // all waves' parts of tile t landed
      __builtin_amdgcn_sched_barrier(0);
      short8 af[4][2], bfr[2][NJ];
#pragma unroll
      for (int i = 0; i < 4; ++i) {
        const int r = wr + i * 16 + fr;
#pragma unroll
        for (int kc = 0; kc < 2; ++kc)
          af[i][kc] = *(const short8*)&Sr[r * 64 + ((((kc << 2) | fq) ^ (r & 7)) << 3)];
      }
#pragma unroll
      for (int j = 0; j < NJ; ++j) {
        const int r = TM + wc + j * 16 + fr;
#pragma unroll
        for (int kc = 0; kc < 2; ++kc)
          bfr[kc][j] = *(const short8*)&Sr[r * 64 + ((((kc << 2) | fq) ^ (r & 7)) << 3)];
      }
      asm volatile("s_waitcnt lgkmcnt(0)" ::: "memory");  // frags in registers
      __builtin_amdgcn_sched_barrier(0);
      __builtin_amdgcn_s_barrier();    // ALL waves done reading Sr -> safe to overwrite
      if (t + 2 < nsteps) stage(Sr, (t + 2) << 6);
      __builtin_amdgcn_s_setprio(1);
#pragma unroll
      for (int kc = 0; kc < 2; ++kc)
#pragma unroll
        for (int i = 0; i < 4; ++i)
#pragma unroll
          for (int j = 0; j < NJ; ++j)
            acc[i][j] = __builtin_amdgcn_mfma_f32_16x16x32_bf16(
                __builtin_bit_cast(bf16x8, af[i][kc]), __builtin_bit_cast(bf16x8, bfr[kc][j]),
                acc[i][j], 0, 0, 0);
      __builtin_amdgcn_s_setprio(0);
      __builtin_amdgcn_sched_barrier(0);
    }
  }

  // C/D layout: col=lane&15, row=(lane>>4)*4+reg (m89/m91 verified)
  const int cr = fq * 4, cc = fr;
#pragma unroll
  for (int i = 0; i < 4; ++i)
#pragma unroll
    for (int j = 0; j < NJ; ++j) {
      const int col = tn + wc + j * 16 + cc;
      const float bv = (col < nbias) ? bias[col] : 0.f;
#pragma unroll
      for (int r = 0; r < 4; ++r) {
        const int row = tm + wr + i * 16 + cr + r;
        float v = acc[i][j][r] + bv;
        if (act) v = fmaxf(v, 0.f);
        Cb[(size_t)row * ldcb + col] = f2bf(v);
      }
    }
}

// ---------------- segment max, XCD feature-sliced ----------------
// Feature dim split into 8 slices of CW; slice c pinned to XCD c via
// blockIdx.x & 7. Per-XCD working set MPAD*CW*2B = 2.6MB/1.3MB < 4MB L2.
// relu'd bf16 >= 0: u16 compare == float compare; 0 == empty-segment fill.
template<int CW>
__global__ __launch_bounds__(256) void aggregate_xcd(
    const u16* __restrict__ m, int ldm, const int* __restrict__ roff,
    const int* __restrict__ esrc, u16* __restrict__ neigh, int ldn) {
  constexpr int TPN = CW / 8;          // threads per node
  constexpr int NPB = 256 / TPN;       // nodes per block
  const int chunk = blockIdx.x & 7;
  const int node = (blockIdx.x >> 3) * NPB + threadIdx.x / TPN;
  if (node >= NN) return;
  const int fi = chunk * CW + (threadIdx.x % TPN) * 8;
  const int beg = roff[node], end = roff[node + 1];
  u16x8 a;
#pragma unroll
  for (int i = 0; i < 8; ++i) a[i] = 0;
  for (int e = beg; e < end; ++e) {
    const u16* row = m + (size_t)esrc[e] * ldm;
    u16x8 v = *(const u16x8*)(row + fi);
#pragma unroll
    for (int i = 0; i < 8; ++i) a[i] = (v[i] > a[i]) ? v[i] : a[i];
  }
  *(u16x8*)(neigh + (size_t)node * ldn + fi) = a;
}

// ---------------- layer 2 output: sigmoid(x2 . Ws2 + neigh2 . Wn2 + b2) ----------------
__global__ __launch_bounds__(256) void final_out(
    const u16* __restrict__ x, const u16* __restrict__ neigh,
    const float* __restrict__ ws, const float* __restrict__ wn,
    const float* __restrict__ b, float* __restrict__ out) {
  const int wave = threadIdx.x >> 6, lane = threadIdx.x & 63;
  const int n = blockIdx.x * 4 + wave;
  if (n >= NN) return;
  const int f = lane * 8;
  const u16* xr = x + (size_t)n * 512 + f;
  const u16* nr = neigh + (size_t)n * 512 + f;
  float s = 0.f;
#pragma unroll
  for (int i = 0; i < 8; ++i)
    s += bf2f(xr[i]) * ws[f + i] + bf2f(nr[i]) * wn[f + i];
#pragma unroll
  for (int o = 32; o > 0; o >>= 1) s += __shfl_xor(s, o);
  if (lane == 0) out[n] = 1.f / (1.f + expf(-(s + b[0])));
}

extern "C" void kernel_launch(void* const* d_in, const int* in_sizes, int n_in,
                              void* d_out, int out_size, void* d_ws, size_t ws_size,
                              hipStream_t stream) {
  const float* h   = (const float*)d_in[0];
  const int*   src = (const int*)d_in[1];
  const int*   dst = (const int*)d_in[2];
  const float* Wp0 = (const float*)d_in[3];
  const float* bp0 = (const float*)d_in[4];
  const float* Ws0 = (const float*)d_in[5];
  const float* Wn0 = (const float*)d_in[6];
  const float* b0  = (const float*)d_in[7];
  const float* Wp1 = (const float*)d_in[8];
  const float* bp1 = (const float*)d_in[9];
  const float* Ws1 = (const float*)d_in[10];
  const float* Wn1 = (const float*)d_in[11];
  const float* b1  = (const float*)d_in[12];
  const float* Wp2 = (const float*)d_in[13];
  const float* bp2 = (const float*)d_in[14];
  const float* Ws2 = (const float*)d_in[15];
  const float* Wn2 = (const float*)d_in[16];
  const float* b2  = (const float*)d_in[17];
  float* out = (float*)d_out;

  char* ws = (char*)d_ws;
  size_t off = 0;
  auto alloc = [&](size_t n) { char* p = ws + off; off = (off + n + 255) & ~(size_t)255; return p; };
  u16* hbf   = (u16*)alloc((size_t)MPAD * 960 * 2);
  u16* x1    = (u16*)alloc((size_t)MPAD * 512 * 2);
  u16* x2    = (u16*)alloc((size_t)MPAD * 512 * 2);
  u16* mbuf  = (u16*)alloc((size_t)MPAD * 1024 * 2);
  u16* nbuf  = (u16*)alloc((size_t)MPAD * 1024 * 2);
  u16* WpT0  = (u16*)alloc((size_t)1024 * 960 * 2);   // [1024 cols][K=960]
  u16* Bcat0 = (u16*)alloc((size_t)512 * 1920 * 2);   // [512][Ws0(960) ; Wn0(960)]
  u16* WpT1  = (u16*)alloc((size_t)512 * 512 * 2);
  u16* Bcat1 = (u16*)alloc((size_t)512 * 1024 * 2);   // [512][Ws1(512) ; Wn1(512)]
  u16* WpT2  = (u16*)alloc((size_t)512 * 512 * 2);
  int* deg   = (int*)alloc(NN * 4);
  int* roff  = (int*)alloc((NN + 1) * 4);
  int* curp  = (int*)alloc(NN * 4);
  int* esrc  = (int*)alloc(NE * 4);

  hipMemsetAsync(deg, 0, NN * 4, stream);
  deg_count<<<NE / 256, 256, 0, stream>>>(dst, deg);
  scan_off<<<1, 256, 0, stream>>>(deg, roff, curp);
  fill_csr<<<NE / 256, 256, 0, stream>>>(src, dst, curp, esrc);
  convert_h<<<(MPAD * 960 / 4) / 256, 256, 0, stream>>>(h, hbf);

  WPack wp;
  wp.d[0] = {Wp0, WpT0,  960, 960, 1024,  960,   0};
  wp.d[1] = {Ws0, Bcat0, 960, 512,  512, 1920,   0};
  wp.d[2] = {Wn0, Bcat0, 960, 512,  512, 1920, 960};
  wp.d[3] = {Wp1, WpT1,  512, 512,  512,  512,   0};
  wp.d[4] = {Ws1, Bcat1, 512, 512,  512, 1024,   0};
  wp.d[5] = {Wn1, Bcat1, 512, 512,  512, 1024, 512};
  wp.d[6] = {Wp2, WpT2,  512, 512,  512,  512,   0};
  transpose_all<<<dim3(32, 30, 7), 256, 0, stream>>>(wp);

  // ---- layer 0 (960 -> 512) ----
  // G1: m0 = relu(hbf @ Wp0 + bp0)  [N=1024 padded, 960 real]
  gemm3<128, 128, 4><<<dim3(8, 79), 512, 0, stream>>>(
      hbf, 960, hbf, 960, 960, WpT0, bp0, 960, mbuf, 1024, 960, 1, 8);
  aggregate_xcd<128><<<5000, 256, 0, stream>>>(mbuf, 1024, roff, esrc, nbuf, 1024);
  // G2: x1 = relu([hbf | nbuf] @ [Ws0;Wn0] + b0)  K = 1920
  gemm3<128, 128, 4><<<dim3(4, 79), 512, 0, stream>>>(
      hbf, 960, nbuf, 1024, 960, Bcat0, b0, 512, x1, 512, 1920, 1, 4);

  // ---- layer 1 (512 -> 512) ----
  gemm3<128, 128, 4><<<dim3(4, 79), 512, 0, stream>>>(
      x1, 512, x1, 512, 512, WpT1, bp1, 512, mbuf, 512, 512, 1, 4);
  aggregate_xcd<64><<<2504, 256, 0, stream>>>(mbuf, 512, roff, esrc, nbuf, 512);
  gemm3<128, 128, 4><<<dim3(4, 79), 512, 0, stream>>>(
      x1, 512, nbuf, 512, 512, Bcat1, b1, 512, x2, 512, 1024, 1, 4);

  // ---- layer 2 (512 -> 1) ----
  gemm3<128, 128, 4><<<dim3(4, 79), 512, 0, stream>>>(
      x2, 512, x2, 512, 512, WpT2, bp2, 512, mbuf, 512, 512, 1, 4);
  aggregate_xcd<64><<<2504, 256, 0, stream>>>(mbuf, 512, roff, esrc, nbuf, 512);
  final_out<<<2500, 256, 0, stream>>>(x2, nbuf, Ws2, Wn2, b2, out);
}

// Round 13
// 228.708 us; speedup vs baseline: 1.8532x; 1.0956x over previous
//
#include <hip/hip_runtime.h>
#include <stdint.h>

#define NN 10000
#define NE 160000
#define MPAD 10112   // 79 * 128 = 158 * 64
#define MTILES 79

typedef unsigned short u16;
typedef float f32x4 __attribute__((ext_vector_type(4)));
typedef short short8 __attribute__((ext_vector_type(8)));
typedef __bf16 bf16x8 __attribute__((ext_vector_type(8)));
typedef unsigned short u16x4 __attribute__((ext_vector_type(4)));
typedef unsigned short u16x8 __attribute__((ext_vector_type(8)));

__device__ __forceinline__ float bf2f(u16 u) {
  union { unsigned u; float f; } c; c.u = ((unsigned)u) << 16; return c.f;
}
__device__ __forceinline__ u16 f2bf(float f) {
  union { float f; unsigned u; } c; c.f = f;
  return (u16)((c.u + 0x7FFFu + ((c.u >> 16) & 1u)) >> 16);
}

__device__ __forceinline__ void gld_lds16(void* lds, const void* g) {
  __builtin_amdgcn_global_load_lds(
      (const unsigned int __attribute__((address_space(1)))*)g,
      (unsigned int __attribute__((address_space(3)))*)lds, 16, 0, 0);
}

// ---------------- CSR build ----------------
__global__ __launch_bounds__(256) void deg_count(const int* __restrict__ dst, int* __restrict__ deg) {
  int e = blockIdx.x * 256 + threadIdx.x;
  if (e < NE) atomicAdd(&deg[dst[e]], 1);
}

// LDS-staged scan: coalesced global loads -> LDS, scan in LDS, coalesced
// flush. (Old version did 2x40 iters of stride-160B uncoalesced global
// access from ONE block - latency-serial.)
__global__ __launch_bounds__(256) void scan_off(const int* __restrict__ deg,
                                                int* __restrict__ roff, int* __restrict__ cur) {
  __shared__ int sdeg[10240];        // 40 KB
  __shared__ int part[256];
  const int t = threadIdx.x;
  for (int k = t; k < NN; k += 256) sdeg[k] = deg[k];
  for (int k = NN + t; k < 10240; k += 256) sdeg[k] = 0;   // pad
  __syncthreads();
  const int CH = 40;
  int s = 0;
#pragma unroll
  for (int i = 0; i < CH; ++i) s += sdeg[t * CH + i];
  part[t] = s; __syncthreads();
  for (int off = 1; off < 256; off <<= 1) {
    int v = (t >= off) ? part[t - off] : 0;
    __syncthreads(); part[t] += v; __syncthreads();
  }
  int run = (t == 0) ? 0 : part[t - 1];
#pragma unroll
  for (int i = 0; i < CH; ++i) {
    const int idx = t * CH + i;
    const int d = sdeg[idx];
    sdeg[idx] = run;                 // exclusive prefix in place
    run += d;
  }
  __syncthreads();
  for (int k = t; k < NN; k += 256) { const int v = sdeg[k]; roff[k] = v; cur[k] = v; }
  if (t == 255) roff[NN] = NE;
}

__global__ __launch_bounds__(256) void fill_csr(const int* __restrict__ src, const int* __restrict__ dst,
                                                int* __restrict__ cur, int* __restrict__ esrc) {
  int e = blockIdx.x * 256 + threadIdx.x;
  if (e < NE) {
    int p = atomicAdd(&cur[dst[e]], 1);
    esrc[p] = src[e];
  }
}

// ---------------- conversions ----------------
// Also zeroes deg[] (first 40 blocks) - replaces the hipMemsetAsync
// dispatch; stream order puts convert_h before deg_count.
__global__ __launch_bounds__(256) void convert_h(const float* __restrict__ h, u16* __restrict__ hbf,
                                                 int* __restrict__ deg) {
  if (blockIdx.x < 40) {
    const int z = blockIdx.x * 256 + threadIdx.x;
    if (z < NN) deg[z] = 0;
  }
  const size_t i = (size_t)(blockIdx.x * 256 + threadIdx.x) * 4;
  if (i >= (size_t)MPAD * 960) return;
  u16x4 o;
  if (i < (size_t)NN * 960) {
    float4 v = *(const float4*)(h + i);
    o[0] = f2bf(v.x); o[1] = f2bf(v.y); o[2] = f2bf(v.z); o[3] = f2bf(v.w);
  } else {
    o[0] = 0; o[1] = 0; o[2] = 0; o[3] = 0;
  }
  *(u16x4*)(hbf + i) = o;
}

// weight transposes, K-concat capable: out[c*ldo + koff + r] = bf16(in[r][c])
struct WDesc { const float* in; u16* out; int R, C, Cpad, ldo, koff; };
struct WPack { WDesc d[7]; };

__global__ __launch_bounds__(256) void transpose_all(WPack p) {
  const WDesc w = p.d[blockIdx.z];
  const int cb = blockIdx.x * 32, rb = blockIdx.y * 32;
  if (cb >= w.Cpad || rb >= w.R) return;
  __shared__ float tile[32][33];
  const int tx = threadIdx.x & 31, ty = threadIdx.x >> 5;
  for (int i = ty; i < 32; i += 8) {
    int r = rb + i, c = cb + tx;
    tile[i][tx] = (r < w.R && c < w.C) ? w.in[(size_t)r * w.C + c] : 0.f;
  }
  __syncthreads();
  for (int i = ty; i < 32; i += 8) {
    int c = cb + i, r = rb + tx;
    if (c < w.Cpad && r < w.R) w.out[(size_t)c * w.ldo + w.koff + r] = f2bf(tile[tx][i]);
  }
}

// ---------------- GEMM: Cb = act(([A0|A1]) @ B^T + bias) ----------------
// FINAL MODEL (rounds 0-11): gemm time == one block's serial phase chain;
// per-CU staging throughput pinned at ~12 B/cy (~7.4 TB/s aggregate) at
// 1.2-2.5 blocks/CU, INVARIANT to: tile shape (r2/r11), BK (r3), pipeline
// depth (r1), wave count (r5: +10% only), staging path (reg-staging r9
// loses; dual-path r10 spills at 4w/EU; B-gather r4 2x loss). The
// byte-x-rate product is flat in every direction. This file = round-5
// config, the measured optimum of the family (251.2us / 250.6us):
// 8-WAVE blocks (512 thr), BK=64, two 32KB buffers, per phase:
//   vmcnt(NC) [tile t landed; t+1 in flight] ; s_barrier ; ds_read tile t ;
//   lgkmcnt(0) ; s_barrier [all waves' frags in regs] ; stage tile t+2
//   into the same buffer ; MFMA (16/wave).
// Swizzle (8x16B slots per 128B row): phys = logical ^ (row&7), same XOR
// on the pre-swizzled global source (rule #21, involution). ksplit%64==0.
// Known non-levers (do not retry): NSTG=4, TM=64, TN=64, BK=32-vs-64 at
// fixed structure, reg-staging in any form at <256-reg budget.
template<int TM, int TN, int MINW>
__global__ __launch_bounds__(512, MINW) void gemm3(
    const u16* __restrict__ A0, int lda0,
    const u16* __restrict__ A1, int lda1, int ksplit,
    const u16* __restrict__ B,
    const float* __restrict__ bias, int nbias,
    u16* __restrict__ Cb, int ldcb,
    int K, int act, int tiles_n) {
  constexpr int TR = TM + TN;        // staged rows per K-tile (256)
  constexpr int NC = TR * 128 / (512 * 16);  // gld instrs per lane per stage (4)
  constexpr int WCOLS = 4;           // 8 waves: 2 rows x 4 cols
  constexpr int WN = TN / WCOLS;     // 32
  constexpr int NJ = WN / 16;        // 2
  constexpr int MT = MPAD / TM;      // M tiles
  __shared__ __align__(16) u16 S0[TR * 64];
  __shared__ __align__(16) u16 S1[TR * 64];
  const int tid = threadIdx.x;
  const int wave = tid >> 6, lane = tid & 63;

  // bijective XCD-chunked swizzle over col-fastest linear id (m204)
  const int nwg = tiles_n * MT;
  const int orig = blockIdx.x + blockIdx.y * tiles_n;
  const int q = nwg >> 3, r8 = nwg & 7;
  const int xcd = orig & 7, idx = orig >> 3;
  const int wg = (xcd < r8 ? xcd * (q + 1) : r8 * (q + 1) + (xcd - r8) * q) + idx;
  const int tm = (wg / tiles_n) * TM;
  const int tn = (wg % tiles_n) * TN;

  const int wr = (wave / WCOLS) * 64;
  const int wc = (wave % WCOLS) * WN;
  const int fr = lane & 15, fq = lane >> 4;
  const int sr8 = lane >> 3;         // row within 8-row wave chunk
  const int sslot = lane & 7;        // 16B slot within 128B row
  f32x4 acc[4][NJ] = {};

  auto stage = [&](u16* Sw, int kk) {
#pragma unroll
    for (int c = 0; c < NC; ++c) {
      const int row = c * 64 + wave * 8 + sr8;                // LDS row
      const int gs = (sslot ^ (row & 7)) * 8;                 // pre-swizzled k-slot
      const void* g;
      if (c < NC * TM / TR) {                                 // A rows (row < TM)
        g = (kk < ksplit)
            ? (const void*)&A0[(size_t)(tm + row) * lda0 + kk + gs]
            : (const void*)&A1[(size_t)(tm + row) * lda1 + (kk - ksplit) + gs];
      } else {                                                // B rows
        g = (const void*)&B[(size_t)(tn + row - TM) * (size_t)K + kk + gs];
      }
      gld_lds16(&Sw[(c * 64 + wave * 8) * 64], g);            // wave-uniform base
    }
  };

  const int nsteps = K >> 6;          // BK=64; all K used are multiples of 64
  stage(S0, 0);
  stage(S1, 64);
  for (int base = 0; base < nsteps; base += 2) {
#pragma unroll
    for (int ph = 0; ph < 2; ++ph) {
      const int t = base + ph;
      if (t >= nsteps) break;
      u16* Sr = (ph == 0) ? S0 : S1;   // holds tile t; also gets tile t+2
      if (t + 1 < nsteps) {
        asm volatile("s_waitcnt vmcnt(%0)" :: "i"(NC) : "memory");  // tile t landed
      } else {
        asm volatile("s_waitcnt vmcnt(0)" ::: "memory");
      }
      __builtin_amdgcn_s_barrier();    // all waves' parts of tile t landed
      __builtin_amdgcn_sched_barrier(0);
      short8 af[4][2], bfr[2][NJ];
#pragma unroll
      for (int i = 0; i < 4; ++i) {
        const int r = wr + i * 16 + fr;
#pragma unroll
        for (int kc = 0; kc < 2; ++kc)
          af[i][kc] = *(const short8*)&Sr[r * 64 + ((((kc << 2) | fq) ^ (r & 7)) << 3)];
      }
#pragma unroll
      for (int j = 0; j < NJ; ++j) {
        const int r = TM + wc + j * 16 + fr;
#pragma unroll
        for (int kc = 0; kc < 2; ++kc)
          bfr[kc][j] = *(const short8*)&Sr[r * 64 + ((((kc << 2) | fq) ^ (r & 7)) << 3)];
      }
      asm volatile("s_waitcnt lgkmcnt(0)" ::: "memory");  // frags in registers
      __builtin_amdgcn_sched_barrier(0);
      __builtin_amdgcn_s_barrier();    // ALL waves done reading Sr -> safe to overwrite
      if (t + 2 < nsteps) stage(Sr, (t + 2) << 6);
      __builtin_amdgcn_s_setprio(1);
#pragma unroll
      for (int kc = 0; kc < 2; ++kc)
#pragma unroll
        for (int i = 0; i < 4; ++i)
#pragma unroll
          for (int j = 0; j < NJ; ++j)
            acc[i][j] = __builtin_amdgcn_mfma_f32_16x16x32_bf16(
                __builtin_bit_cast(bf16x8, af[i][kc]), __builtin_bit_cast(bf16x8, bfr[kc][j]),
                acc[i][j], 0, 0, 0);
      __builtin_amdgcn_s_setprio(0);
      __builtin_amdgcn_sched_barrier(0);
    }
  }

  // C/D layout: col=lane&15, row=(lane>>4)*4+reg (m89/m91 verified)
  const int cr = fq * 4, cc = fr;
#pragma unroll
  for (int i = 0; i < 4; ++i)
#pragma unroll
    for (int j = 0; j < NJ; ++j) {
      const int col = tn + wc + j * 16 + cc;
      const float bv = (col < nbias) ? bias[col] : 0.f;
#pragma unroll
      for (int r = 0; r < 4; ++r) {
        const int row = tm + wr + i * 16 + cr + r;
        float v = acc[i][j][r] + bv;
        if (act) v = fmaxf(v, 0.f);
        Cb[(size_t)row * ldcb + col] = f2bf(v);
      }
    }
}

// ---------------- segment max, XCD feature-sliced ----------------
// Feature dim split into 8 slices of CW; slice c pinned to XCD c via
// blockIdx.x & 7. Per-XCD working set MPAD*CW*2B = 2.6MB/1.3MB < 4MB L2.
// relu'd bf16 >= 0: u16 compare == float compare; 0 == empty-segment fill.
template<int CW>
__global__ __launch_bounds__(256) void aggregate_xcd(
    const u16* __restrict__ m, int ldm, const int* __restrict__ roff,
    const int* __restrict__ esrc, u16* __restrict__ neigh, int ldn) {
  constexpr int TPN = CW / 8;          // threads per node
  constexpr int NPB = 256 / TPN;       // nodes per block
  const int chunk = blockIdx.x & 7;
  const int node = (blockIdx.x >> 3) * NPB + threadIdx.x / TPN;
  if (node >= NN) return;
  const int fi = chunk * CW + (threadIdx.x % TPN) * 8;
  const int beg = roff[node], end = roff[node + 1];
  u16x8 a;
#pragma unroll
  for (int i = 0; i < 8; ++i) a[i] = 0;
  for (int e = beg; e < end; ++e) {
    const u16* row = m + (size_t)esrc[e] * ldm;
    u16x8 v = *(const u16x8*)(row + fi);
#pragma unroll
    for (int i = 0; i < 8; ++i) a[i] = (v[i] > a[i]) ? v[i] : a[i];
  }
  *(u16x8*)(neigh + (size_t)node * ldn + fi) = a;
}

// ---------------- layer 2 fused: aggregate + sigmoid(x2.Ws2 + neigh.Wn2 + b2) ----
// One wave per node: 64 lanes x 8 features hold the segment-max in
// registers (from mbuf, ld=512), then the two dot products + wave reduce.
// Replaces aggregate_xcd<64> + final_out: saves the nbuf write+read
// roundtrip (~21MB) and one dispatch. mbuf slice = 10.2MB, L2-resident.
__global__ __launch_bounds__(256) void agg_final(
    const u16* __restrict__ m, const int* __restrict__ roff,
    const int* __restrict__ esrc, const u16* __restrict__ x,
    const float* __restrict__ ws, const float* __restrict__ wn,
    const float* __restrict__ b, float* __restrict__ out) {
  const int wave = threadIdx.x >> 6, lane = threadIdx.x & 63;
  const int n = blockIdx.x * 4 + wave;
  if (n >= NN) return;
  const int f = lane * 8;
  const int beg = roff[n], end = roff[n + 1];
  u16x8 a;
#pragma unroll
  for (int i = 0; i < 8; ++i) a[i] = 0;
  for (int e = beg; e < end; ++e) {
    u16x8 v = *(const u16x8*)(m + (size_t)esrc[e] * 512 + f);
#pragma unroll
    for (int i = 0; i < 8; ++i) a[i] = (v[i] > a[i]) ? v[i] : a[i];
  }
  const u16x8 xv = *(const u16x8*)(x + (size_t)n * 512 + f);
  float s = 0.f;
#pragma unroll
  for (int i = 0; i < 8; ++i)
    s += bf2f(xv[i]) * ws[f + i] + bf2f(a[i]) * wn[f + i];
#pragma unroll
  for (int o = 32; o > 0; o >>= 1) s += __shfl_xor(s, o);
  if (lane == 0) out[n] = 1.f / (1.f + expf(-(s + b[0])));
}

extern "C" void kernel_launch(void* const* d_in, const int* in_sizes, int n_in,
                              void* d_out, int out_size, void* d_ws, size_t ws_size,
                              hipStream_t stream) {
  const float* h   = (const float*)d_in[0];
  const int*   src = (const int*)d_in[1];
  const int*   dst = (const int*)d_in[2];
  const float* Wp0 = (const float*)d_in[3];
  const float* bp0 = (const float*)d_in[4];
  const float* Ws0 = (const float*)d_in[5];
  const float* Wn0 = (const float*)d_in[6];
  const float* b0  = (const float*)d_in[7];
  const float* Wp1 = (const float*)d_in[8];
  const float* bp1 = (const float*)d_in[9];
  const float* Ws1 = (const float*)d_in[10];
  const float* Wn1 = (const float*)d_in[11];
  const float* b1  = (const float*)d_in[12];
  const float* Wp2 = (const float*)d_in[13];
  const float* bp2 = (const float*)d_in[14];
  const float* Ws2 = (const float*)d_in[15];
  const float* Wn2 = (const float*)d_in[16];
  const float* b2  = (const float*)d_in[17];
  float* out = (float*)d_out;

  char* ws = (char*)d_ws;
  size_t off = 0;
  auto alloc = [&](size_t n) { char* p = ws + off; off = (off + n + 255) & ~(size_t)255; return p; };
  u16* hbf   = (u16*)alloc((size_t)MPAD * 960 * 2);
  u16* x1    = (u16*)alloc((size_t)MPAD * 512 * 2);
  u16* x2    = (u16*)alloc((size_t)MPAD * 512 * 2);
  u16* mbuf  = (u16*)alloc((size_t)MPAD * 1024 * 2);
  u16* nbuf  = (u16*)alloc((size_t)MPAD * 1024 * 2);
  u16* WpT0  = (u16*)alloc((size_t)1024 * 960 * 2);   // [1024 cols][K=960]
  u16* Bcat0 = (u16*)alloc((size_t)512 * 1920 * 2);   // [512][Ws0(960) ; Wn0(960)]
  u16* WpT1  = (u16*)alloc((size_t)512 * 512 * 2);
  u16* Bcat1 = (u16*)alloc((size_t)512 * 1024 * 2);   // [512][Ws1(512) ; Wn1(512)]
  u16* WpT2  = (u16*)alloc((size_t)512 * 512 * 2);
  int* deg   = (int*)alloc(NN * 4);
  int* roff  = (int*)alloc((NN + 1) * 4);
  int* curp  = (int*)alloc(NN * 4);
  int* esrc  = (int*)alloc(NE * 4);

  convert_h<<<(MPAD * 960 / 4) / 256, 256, 0, stream>>>(h, hbf, deg);  // also zeroes deg
  deg_count<<<NE / 256, 256, 0, stream>>>(dst, deg);
  scan_off<<<1, 256, 0, stream>>>(deg, roff, curp);
  fill_csr<<<NE / 256, 256, 0, stream>>>(src, dst, curp, esrc);

  WPack wp;
  wp.d[0] = {Wp0, WpT0,  960, 960, 1024,  960,   0};
  wp.d[1] = {Ws0, Bcat0, 960, 512,  512, 1920,   0};
  wp.d[2] = {Wn0, Bcat0, 960, 512,  512, 1920, 960};
  wp.d[3] = {Wp1, WpT1,  512, 512,  512,  512,   0};
  wp.d[4] = {Ws1, Bcat1, 512, 512,  512, 1024,   0};
  wp.d[5] = {Wn1, Bcat1, 512, 512,  512, 1024, 512};
  wp.d[6] = {Wp2, WpT2,  512, 512,  512,  512,   0};
  transpose_all<<<dim3(32, 30, 7), 256, 0, stream>>>(wp);

  // ---- layer 0 (960 -> 512) ----
  // G1: m0 = relu(hbf @ Wp0 + bp0)  [N=1024 padded, 960 real]
  gemm3<128, 128, 4><<<dim3(8, 79), 512, 0, stream>>>(
      hbf, 960, hbf, 960, 960, WpT0, bp0, 960, mbuf, 1024, 960, 1, 8);
  aggregate_xcd<128><<<5000, 256, 0, stream>>>(mbuf, 1024, roff, esrc, nbuf, 1024);
  // G2: x1 = relu([hbf | nbuf] @ [Ws0;Wn0] + b0)  K = 1920
  gemm3<128, 128, 4><<<dim3(4, 79), 512, 0, stream>>>(
      hbf, 960, nbuf, 1024, 960, Bcat0, b0, 512, x1, 512, 1920, 1, 4);

  // ---- layer 1 (512 -> 512) ----
  gemm3<128, 128, 4><<<dim3(4, 79), 512, 0, stream>>>(
      x1, 512, x1, 512, 512, WpT1, bp1, 512, mbuf, 512, 512, 1, 4);
  aggregate_xcd<64><<<2504, 256, 0, stream>>>(mbuf, 512, roff, esrc, nbuf, 512);
  gemm3<128, 128, 4><<<dim3(4, 79), 512, 0, stream>>>(
      x1, 512, nbuf, 512, 512, Bcat1, b1, 512, x2, 512, 1024, 1, 4);

  // ---- layer 2 (512 -> 1) ----
  gemm3<128, 128, 4><<<dim3(4, 79), 512, 0, stream>>>(
      x2, 512, x2, 512, 512, WpT2, bp2, 512, mbuf, 512, 512, 1, 4);
  agg_final<<<2500, 256, 0, stream>>>(mbuf, roff, esrc, x2, Ws2, Wn2, b2, out);
}